// Round 5
// baseline (620.826 us; speedup 1.0000x reference)
//
#include <hip/hip_runtime.h>
#include <cstdint>
#include <cstddef>

#define NB 128
#define NT 512
#define NJ 21
#define NC 3
#define NH 64
#define JH 1344   // NJ*NH
#define G3 192    // 3*NH
#define OUT0 (NB*NJ*NC) // 8064
#define FB 4      // frames per k1 block (one per wave)

typedef __attribute__((ext_vector_type(8))) __bf16 bf16x8;
typedef __attribute__((ext_vector_type(4))) float f32x4;

__device__ __forceinline__ float bf2f(unsigned short u) {
  union { unsigned int i; float f; } v; v.i = ((unsigned int)u) << 16; return v.f;
}
__device__ __forceinline__ unsigned short f2bf(float f) {
  union { float f; unsigned int i; } v; v.f = f;
  unsigned int x = v.i;
  unsigned int lsb = (x >> 16) & 1u;
  x += 0x7fffu + lsb;
  return (unsigned short)(x >> 16);
}
__device__ __forceinline__ unsigned int pk_bf16(float lo, float hi) {
  unsigned int r;
  asm("v_cvt_pk_bf16_f32 %0, %1, %2" : "=v"(r) : "v"(lo), "v"(hi));
  return r;
}
__device__ __forceinline__ unsigned int scale2(unsigned int u, float s) {
  float lo = __uint_as_float(u << 16);
  float hi = __uint_as_float(u & 0xffff0000u);
  return pk_bf16(lo * s, hi * s);
}

// ---------------- K0: convert W_ih (192x1344 f32) to bf16
__global__ __launch_bounds__(256) void k0_convw(
    const float* __restrict__ W, unsigned short* __restrict__ Wbf) {
  const int ti = blockIdx.x*256 + threadIdx.x;
  const float4 v = ((const float4*)W)[ti];
  uint2 o;
  o.x = (unsigned int)f2bf(v.x) | ((unsigned int)f2bf(v.y) << 16);
  o.y = (unsigned int)f2bf(v.z) | ((unsigned int)f2bf(v.w) << 16);
  ((uint2*)Wbf)[ti] = o;
}

// ---------------- K1: fused GCN x2 via MFMA, linear padded LDS (no swizzle).
__global__ __launch_bounds__(256, 2) void k1_fused(
    const float* __restrict__ x, const float* __restrict__ A,
    const float* __restrict__ W1, const float* __restrict__ b1,
    const float* __restrict__ W2, const float* __restrict__ b2,
    const float* __restrict__ Wa,
    unsigned short* __restrict__ h2out, float* __restrict__ scorepart) {
  __shared__ unsigned short h1s[FB*32*72];   // 18 KB  [row][72]
  __shared__ unsigned short us[FB*64*40];    // 20 KB  us[f][h][40]
  __shared__ unsigned short w2s[64*72];      // 9 KB   [h][72]
  __shared__ unsigned short adjs[32*40];     // 2.5 KB [i][40]
  __shared__ unsigned short h2st[FB*NJ*72];  // 11.8 KB [f*21+i][72]
  __shared__ float afs[NJ*NJ];
  __shared__ float xs[4][64];
  __shared__ float ags[4][64];
  __shared__ float spred[4][NJ];

  const int tid = threadIdx.x;
  const int w = tid >> 6, l = tid & 63;
  const int q = l >> 4, r = l & 15;
  const int b = blockIdx.x >> 7, ch = blockIdx.x & 127;
  const int t0 = ch * FB;

  // ---- stage constants
  for (int i = tid; i < NJ*NJ; i += 256) afs[i] = A[i];
  for (int i = tid; i < 1024; i += 256) {
    const int ii = i >> 5, jj = i & 31;
    adjs[ii*40 + jj] = (ii < NJ && jj < NJ) ? f2bf(A[ii*NJ + jj]) : (unsigned short)0;
  }
  {
    const int h = tid & 63, qd = tid >> 6;
    const int g0 = qd * 16;
#pragma unroll
    for (int e = 0; e < 16; e += 2) {
      const float v0 = W2[h*64 + g0 + e], v1 = W2[h*64 + g0 + e + 1];
      ((unsigned int*)w2s)[h*36 + ((g0 + e) >> 1)] = pk_bf16(v0, v1);
    }
  }
#pragma unroll
  for (int j = NJ; j < 32; ++j)
    ((unsigned int*)h1s)[(w*32 + j)*36 + (l & 31)] = 0u;

  const float w1r0 = W1[l*3+0], w1r1 = W1[l*3+1], w1r2 = W1[l*3+2];
  const float b1h = b1[l];
  float b2v[4][4], wav[4][4];
#pragma unroll
  for (int mt = 0; mt < 4; ++mt)
#pragma unroll
    for (int rg = 0; rg < 4; ++rg) {
      const int h = mt*16 + q*4 + rg;
      b2v[mt][rg] = b2[h]; wav[mt][rg] = Wa[h];
    }
  __syncthreads();   // B0: constants ready

  // ---- layer 1 (VALU), frame f = w
  {
    const size_t fr = (size_t)(b*NT + t0 + w);
    if (l < NJ*NC) xs[w][l] = x[fr*(NJ*NC) + l];
    if (l < NJ*NC) {
      const int ji = l / 3, c = l - ji*3;
      float s = 0.f;
#pragma unroll
      for (int j = 0; j < NJ; ++j) s += afs[ji*NJ + j] * xs[w][j*3 + c];
      ags[w][l] = s;
    }
#pragma unroll
    for (int j = 0; j < NJ; ++j) {
      float v = b1h + w1r0*ags[w][j*3+0] + w1r1*ags[w][j*3+1] + w1r2*ags[w][j*3+2];
      v = fmaxf(v, 0.f);
      h1s[(w*32 + j)*72 + l] = f2bf(v);
    }
  }
  __syncthreads();   // B1: h1s ready

  // ---- GEMM-1 (MFMA): u = h1 @ W2^T  (wave m-tiles 2w, 2w+1)
  bf16x8 bw[2][4];
#pragma unroll
  for (int ks = 0; ks < 2; ++ks)
#pragma unroll
    for (int nt = 0; nt < 4; ++nt)
      bw[ks][nt] = *(const bf16x8*)(&w2s[(nt*16 + r)*72 + (ks*4 + q)*8]);
  f32x4 acc1[2][4];
#pragma unroll
  for (int i = 0; i < 2; ++i)
#pragma unroll
    for (int j2 = 0; j2 < 4; ++j2) acc1[i][j2] = (f32x4)0.f;
#pragma unroll
  for (int mti = 0; mti < 2; ++mti) {
    const int row = (w*2 + mti)*16 + r;
#pragma unroll
    for (int ks = 0; ks < 2; ++ks) {
      const bf16x8 af = *(const bf16x8*)(&h1s[row*72 + (ks*4 + q)*8]);
#pragma unroll
      for (int nt = 0; nt < 4; ++nt)
        acc1[mti][nt] = __builtin_amdgcn_mfma_f32_16x16x32_bf16(af, bw[ks][nt], acc1[mti][nt], 0,0,0);
    }
  }
#pragma unroll
  for (int mti = 0; mti < 2; ++mti)
#pragma unroll
    for (int nt = 0; nt < 4; ++nt) {
      const int h = nt*16 + r;
#pragma unroll
      for (int rp = 0; rp < 2; ++rp) {
        const int jp = mti*16 + q*4 + rp*2;
        ((unsigned int*)us)[(w*64 + h)*20 + (jp >> 1)] =
            pk_bf16(acc1[mti][nt][rp*2], acc1[mti][nt][rp*2+1]);
      }
    }
  __syncthreads();   // B2: us ready

  // ---- A-agg (MFMA): D2[h][i] = sum_j u[j][h] * Aadj[i][j]
  bf16x8 badj[2];
#pragma unroll
  for (int nt = 0; nt < 2; ++nt)
    badj[nt] = *(const bf16x8*)(&adjs[(nt*16 + r)*40 + q*8]);
  f32x4 acc2[4][2];
#pragma unroll
  for (int i = 0; i < 4; ++i) { acc2[i][0] = (f32x4)0.f; acc2[i][1] = (f32x4)0.f; }
#pragma unroll
  for (int mt = 0; mt < 4; ++mt) {
    const int h = mt*16 + r;
    const bf16x8 af = *(const bf16x8*)(&us[(w*64 + h)*40 + q*8]);
#pragma unroll
    for (int nt = 0; nt < 2; ++nt)
      acc2[mt][nt] = __builtin_amdgcn_mfma_f32_16x16x32_bf16(af, badj[nt], acc2[mt][nt], 0,0,0);
  }
  float sp0 = 0.f, sp1 = 0.f;
#pragma unroll
  for (int nt = 0; nt < 2; ++nt) {
    const int i = nt*16 + r;
    if (i < NJ) {
#pragma unroll
      for (int mt = 0; mt < 4; ++mt)
#pragma unroll
        for (int rp = 0; rp < 2; ++rp) {
          const int h0 = mt*16 + q*4 + rp*2;
          const float v0 = fmaxf(acc2[mt][nt][rp*2]   + b2v[mt][rp*2],   0.f);
          const float v1 = fmaxf(acc2[mt][nt][rp*2+1] + b2v[mt][rp*2+1], 0.f);
          if (nt == 0) sp0 += v0*wav[mt][rp*2] + v1*wav[mt][rp*2+1];
          else         sp1 += v0*wav[mt][rp*2] + v1*wav[mt][rp*2+1];
          ((unsigned int*)h2st)[(w*NJ + i)*36 + (h0 >> 1)] = pk_bf16(v0, v1);
        }
    }
  }
  sp0 += __shfl_xor(sp0, 16); sp0 += __shfl_xor(sp0, 32);
  sp1 += __shfl_xor(sp1, 16); sp1 += __shfl_xor(sp1, 32);
  if (l < 16) spred[w][l] = sp0;
  if (l < 5)  spred[w][16 + l] = sp1;
  __syncthreads();   // B3: h2st + spred ready

  if (tid < NJ)
    scorepart[((size_t)b*128 + ch)*NJ + tid] =
      spred[0][tid] + spred[1][tid] + spred[2][tid] + spred[3][tid];

  const size_t gbase = (size_t)(b*NT + t0) * JH;
  for (int cid = tid; cid < FB*NJ*8; cid += 256) {
    const int f = cid / (NJ*8), rem = cid - f*(NJ*8);
    const int i = rem >> 3, p = rem & 7;
    const uint4 v = *(const uint4*)(&h2st[(f*NJ + i)*72 + p*8]);
    *(uint4*)(&h2out[gbase + (size_t)f*JH + i*64 + p*8]) = v;
  }
}

// ---------------- K2: reduce score partials, softmax over joints
__global__ __launch_bounds__(64) void k2_attn(
    const float* __restrict__ scorepart, float* __restrict__ attn,
    float* __restrict__ out_attn) {
  __shared__ float ss[NJ];
  const int b = blockIdx.x, tid = threadIdx.x;
  if (tid < NJ) {
    float s = 0.f;
    for (int ch = 0; ch < 128; ++ch) s += scorepart[(b*128 + ch)*NJ + tid];
    ss[tid] = s * (1.0f/NT);
  }
  __syncthreads();
  float m = -1e30f;
  for (int j = 0; j < NJ; ++j) m = fmaxf(m, ss[j]);
  float sum = 0.f;
  for (int j = 0; j < NJ; ++j) sum += expf(ss[j] - m);
  if (tid < NJ) {
    float a = expf(ss[tid] - m) / sum;
    attn[b*NJ + tid] = a;
    out_attn[b*NJ + tid] = a;
  }
}

// ---------------- K3: xproj = (h2 * attn) @ W_ih.T + b_ih  -- MFMA bf16
__global__ __launch_bounds__(256, 2) void k3_xproj_mfma(
    const unsigned short* __restrict__ h2, const unsigned short* __restrict__ Wbf,
    const float* __restrict__ b_ih, const float* __restrict__ attn,
    float* __restrict__ xproj) {
  __shared__ unsigned short Abuf[2][128*32];
  __shared__ unsigned short Bbuf[2][192*32];
  const int tid = threadIdx.x;
  const int w = tid >> 6, l = tid & 63;
  const int lq = l >> 4, lr = l & 15;
  const int blk = blockIdx.x;
  const int b = blk >> 2;
  const int t0 = (blk & 3) << 7;
  const int wm = w >> 1, wn = w & 1;

  const unsigned short* gA[2]; int ldsA[2];
#pragma unroll
  for (int i = 0; i < 2; ++i) {
    const int lc = tid*2 + i, rr = lc >> 2, j = lc & 3;
    gA[i] = h2 + (size_t)(b*NT + t0 + rr)*JH + j*8;
    ldsA[i] = rr*32 + ((j ^ ((rr>>1)&3)) << 3);
  }
  const unsigned short* gB[3]; int ldsB[3];
#pragma unroll
  for (int i = 0; i < 3; ++i) {
    const int lc = tid + 256*i, g = lc >> 2, j = lc & 3;
    gB[i] = Wbf + (size_t)g*JH + j*8;
    ldsB[i] = g*32 + ((j ^ ((g>>1)&3)) << 3);
  }
  int aoff[4], boff[6];
#pragma unroll
  for (int mt = 0; mt < 4; ++mt) {
    const int row = wm*64 + mt*16 + lr;
    aoff[mt] = row*32 + ((lq ^ ((row>>1)&3)) << 3);
  }
#pragma unroll
  for (int nt = 0; nt < 6; ++nt) {
    const int g = wn*96 + nt*16 + lr;
    boff[nt] = g*32 + ((lq ^ ((g>>1)&3)) << 3);
  }

  f32x4 acc[4][6];
#pragma unroll
  for (int mt = 0; mt < 4; ++mt)
#pragma unroll
    for (int nt = 0; nt < 6; ++nt) acc[mt][nt] = (f32x4)0.f;

  {
    const float s = attn[b*NJ + 0];
#pragma unroll
    for (int i = 0; i < 2; ++i)
      *(uint4*)(&Abuf[0][ldsA[i]]) = *(const uint4*)(gA[i]);
#pragma unroll
    for (int i = 0; i < 3; ++i) {
      uint4 v = *(const uint4*)(gB[i]);
      v.x = scale2(v.x, s); v.y = scale2(v.y, s);
      v.z = scale2(v.z, s); v.w = scale2(v.w, s);
      *(uint4*)(&Bbuf[0][ldsB[i]]) = v;
    }
  }
  __syncthreads();

  for (int ks = 0; ks < 42; ++ks) {
    const int cur = ks & 1;
    uint4 av0, av1, bv0, bv1, bv2;
    if (ks < 41) {
      const int kk = (ks+1)*32;
      av0 = *(const uint4*)(gA[0] + kk);
      av1 = *(const uint4*)(gA[1] + kk);
      bv0 = *(const uint4*)(gB[0] + kk);
      bv1 = *(const uint4*)(gB[1] + kk);
      bv2 = *(const uint4*)(gB[2] + kk);
    }
    bf16x8 af[4], bfr[6];
#pragma unroll
    for (int mt = 0; mt < 4; ++mt) af[mt] = *(const bf16x8*)(&Abuf[cur][aoff[mt]]);
#pragma unroll
    for (int nt = 0; nt < 6; ++nt) bfr[nt] = *(const bf16x8*)(&Bbuf[cur][boff[nt]]);
#pragma unroll
    for (int mt = 0; mt < 4; ++mt)
#pragma unroll
      for (int nt = 0; nt < 6; ++nt)
        acc[mt][nt] = __builtin_amdgcn_mfma_f32_16x16x32_bf16(af[mt], bfr[nt], acc[mt][nt], 0, 0, 0);
    if (ks < 41) {
      const float s = attn[b*NJ + ((ks+1) >> 1)];
      *(uint4*)(&Abuf[cur^1][ldsA[0]]) = av0;
      *(uint4*)(&Abuf[cur^1][ldsA[1]]) = av1;
      uint4 v;
      v = bv0; v.x = scale2(v.x, s); v.y = scale2(v.y, s); v.z = scale2(v.z, s); v.w = scale2(v.w, s);
      *(uint4*)(&Bbuf[cur^1][ldsB[0]]) = v;
      v = bv1; v.x = scale2(v.x, s); v.y = scale2(v.y, s); v.z = scale2(v.z, s); v.w = scale2(v.w, s);
      *(uint4*)(&Bbuf[cur^1][ldsB[1]]) = v;
      v = bv2; v.x = scale2(v.x, s); v.y = scale2(v.y, s); v.z = scale2(v.z, s); v.w = scale2(v.w, s);
      *(uint4*)(&Bbuf[cur^1][ldsB[2]]) = v;
    }
    __syncthreads();
  }

  float bias[6];
#pragma unroll
  for (int nt = 0; nt < 6; ++nt) bias[nt] = b_ih[wn*96 + nt*16 + lr];
#pragma unroll
  for (int mt = 0; mt < 4; ++mt)
#pragma unroll
    for (int nt = 0; nt < 6; ++nt) {
      const int g = wn*96 + nt*16 + lr;
#pragma unroll
      for (int rr = 0; rr < 4; ++rr) {
        const int trow = t0 + wm*64 + mt*16 + lq*4 + rr;
        xproj[(size_t)(b*NT + trow)*G3 + g] = acc[mt][nt][rr] + bias[nt];
      }
    }
}

// ---------------- K4: GRU, one WAVE per batch. Lane g owns channel g and
// holds W_hh rows {g, 64+g, 128+g} in 192 fp32 VGPRs. h broadcast via LDS
// (wave-synchronous, single barrier as fence). xproj prefetched 4 steps deep
// (static unroll), biases folded into prefetch. Fast sigmoid/tanh via __expf.
__global__ __launch_bounds__(64, 1) void k4_gru_wave(
    const float* __restrict__ xproj, const float* __restrict__ W_hh,
    const float* __restrict__ b_hh, float* __restrict__ hT) {
  __shared__ __align__(16) float hs[NH];
  const int b = blockIdx.x, g = threadIdx.x;

  float wr[NH], wz[NH], wn[NH];
  {
    const float4* pr = (const float4*)(W_hh + (size_t)g*NH);
    const float4* pz = (const float4*)(W_hh + (size_t)(NH + g)*NH);
    const float4* pn = (const float4*)(W_hh + (size_t)(2*NH + g)*NH);
#pragma unroll
    for (int q = 0; q < 16; ++q) {
      const float4 vr = pr[q], vz = pz[q], vn = pn[q];
      wr[4*q+0]=vr.x; wr[4*q+1]=vr.y; wr[4*q+2]=vr.z; wr[4*q+3]=vr.w;
      wz[4*q+0]=vz.x; wz[4*q+1]=vz.y; wz[4*q+2]=vz.z; wz[4*q+3]=vz.w;
      wn[4*q+0]=vn.x; wn[4*q+1]=vn.y; wn[4*q+2]=vn.z; wn[4*q+3]=vn.w;
    }
  }
  const float br = b_hh[g], bz = b_hh[NH + g], bn = b_hh[2*NH + g];
  const float* xb = xproj + (size_t)b*NT*G3;

  hs[g] = 0.f;
  float hprev = 0.f;
  // 4-deep prefetch, biases folded
  float pxr[4], pxz[4], pxn[4];
#pragma unroll
  for (int p = 0; p < 4; ++p) {
    pxr[p] = xb[(size_t)p*G3 + g] + br;
    pxz[p] = xb[(size_t)p*G3 + NH + g] + bz;
    pxn[p] = xb[(size_t)p*G3 + 2*NH + g] + bn;
  }
  __syncthreads();

  for (int t = 0; t < NT; t += 4) {
#pragma unroll
    for (int p = 0; p < 4; ++p) {
      int tf = t + 4 + p; if (tf >= NT) tf = NT - 1;   // harmless re-read
      const float nxr = xb[(size_t)tf*G3 + g];
      const float nxz = xb[(size_t)tf*G3 + NH + g];
      const float nxn = xb[(size_t)tf*G3 + 2*NH + g];

      float ar0=0.f, ar1=0.f, az0=0.f, az1=0.f, an0=0.f, an1=0.f;
      const float4* h4 = (const float4*)hs;
#pragma unroll
      for (int q = 0; q < 16; q += 2) {
        const float4 v0 = h4[q], v1 = h4[q+1];
        ar0 += v0.x*wr[4*q+0] + v0.y*wr[4*q+1] + v0.z*wr[4*q+2] + v0.w*wr[4*q+3];
        az0 += v0.x*wz[4*q+0] + v0.y*wz[4*q+1] + v0.z*wz[4*q+2] + v0.w*wz[4*q+3];
        an0 += v0.x*wn[4*q+0] + v0.y*wn[4*q+1] + v0.z*wn[4*q+2] + v0.w*wn[4*q+3];
        ar1 += v1.x*wr[4*q+4] + v1.y*wr[4*q+5] + v1.z*wr[4*q+6] + v1.w*wr[4*q+7];
        az1 += v1.x*wz[4*q+4] + v1.y*wz[4*q+5] + v1.z*wz[4*q+6] + v1.w*wz[4*q+7];
        an1 += v1.x*wn[4*q+4] + v1.y*wn[4*q+5] + v1.z*wn[4*q+6] + v1.w*wn[4*q+7];
      }
      const float hr = ar0 + ar1, hz = az0 + az1, hn = an0 + an1;
      const float rr = 1.f/(1.f + __expf(-(pxr[p] + hr)));
      const float zz = 1.f/(1.f + __expf(-(pxz[p] + hz)));
      const float nx = pxn[p] + rr*hn;
      const float nn = 2.f/(1.f + __expf(-2.f*nx)) - 1.f;   // tanh
      hprev = (1.f - zz)*nn + zz*hprev;
      hs[g] = hprev;
      __syncthreads();   // single wave: fence only (orders LDS write vs next reads)
      pxr[p] = nxr + br; pxz[p] = nxz + bz; pxn[p] = nxn + bn;
    }
  }
  hT[b*NH + g] = hprev;
}

// ---------------- K5: head
__global__ __launch_bounds__(256) void k5_head(
    const float* __restrict__ hT, const float* __restrict__ W_head,
    const float* __restrict__ b_head, float* __restrict__ out) {
  const int idx = blockIdx.x*256 + threadIdx.x;
  if (idx >= NB*63) return;
  const int b = idx / 63, rr = idx % 63;
  const float* hv = hT + b*NH;
  const float* wr = W_head + rr*NH;
  float acc = b_head[rr];
#pragma unroll
  for (int k = 0; k < NH; ++k) acc += hv[k]*wr[k];
  out[idx] = acc;
}

extern "C" void kernel_launch(void* const* d_in, const int* in_sizes, int n_in,
                              void* d_out, int out_size, void* d_ws, size_t ws_size,
                              hipStream_t stream) {
  const float* x      = (const float*)d_in[0];
  const float* A      = (const float*)d_in[1];
  const float* W1     = (const float*)d_in[2];
  const float* b1     = (const float*)d_in[3];
  const float* W2     = (const float*)d_in[4];
  const float* b2     = (const float*)d_in[5];
  const float* Wa     = (const float*)d_in[6];
  // d_in[7] = ba : softmax-invariant, unused
  const float* W_ih   = (const float*)d_in[8];
  const float* b_ih   = (const float*)d_in[9];
  const float* W_hh   = (const float*)d_in[10];
  const float* b_hh   = (const float*)d_in[11];
  const float* W_head = (const float*)d_in[12];
  const float* b_head = (const float*)d_in[13];
  float* out = (float*)d_out;

  char* ws = (char*)d_ws;
  size_t off = 0;
  unsigned short* h2 = (unsigned short*)(ws + off); off += (size_t)NB*NT*JH*2;   // 176 MB
  float* scorepart   = (float*)(ws + off);          off += (size_t)NB*128*NJ*4;  // 1.38 MB
  float* attn        = (float*)(ws + off);          off += (size_t)NB*NJ*4;
  off = (off + 15) & ~(size_t)15;
  float* xproj       = (float*)(ws + off);          off += (size_t)NB*NT*G3*4;   // 50 MB
  float* hT          = (float*)(ws + off);          off += (size_t)NB*NH*4;
  off = (off + 15) & ~(size_t)15;
  unsigned short* Wbf = (unsigned short*)(ws + off); off += (size_t)G3*JH*2;     // 516 KB

  k0_convw<<<dim3(252),       256, 0, stream>>>(W_ih, Wbf);
  k1_fused<<<dim3(NB*128),    256, 0, stream>>>(x, A, W1, b1, W2, b2, Wa, h2, scorepart);
  k2_attn<<<dim3(NB),          64, 0, stream>>>(scorepart, attn, out + OUT0);
  k3_xproj_mfma<<<dim3(512),  256, 0, stream>>>(h2, Wbf, b_ih, attn, xproj);
  k4_gru_wave<<<dim3(NB),      64, 0, stream>>>(xproj, W_hh, b_hh, hT);
  k5_head<<<dim3((NB*63 + 255)/256), 256, 0, stream>>>(hT, W_head, b_head, out);
}

// Round 6
// 605.029 us; speedup vs baseline: 1.0261x; 1.0261x over previous
//
#include <hip/hip_runtime.h>
#include <cstdint>
#include <cstddef>

#define NB 128
#define NT 512
#define NJ 21
#define NC 3
#define NH 64
#define JH 1344   // NJ*NH
#define G3 192    // 3*NH
#define OUT0 (NB*NJ*NC) // 8064
#define FB 4      // frames per k1 block (one per wave)

typedef __attribute__((ext_vector_type(8))) __bf16 bf16x8;
typedef __attribute__((ext_vector_type(4))) float f32x4;

__device__ __forceinline__ float bf2f(unsigned short u) {
  union { unsigned int i; float f; } v; v.i = ((unsigned int)u) << 16; return v.f;
}
__device__ __forceinline__ unsigned short f2bf(float f) {
  union { float f; unsigned int i; } v; v.f = f;
  unsigned int x = v.i;
  unsigned int lsb = (x >> 16) & 1u;
  x += 0x7fffu + lsb;
  return (unsigned short)(x >> 16);
}
__device__ __forceinline__ unsigned int pk_bf16(float lo, float hi) {
  unsigned int r;
  asm("v_cvt_pk_bf16_f32 %0, %1, %2" : "=v"(r) : "v"(lo), "v"(hi));
  return r;
}
__device__ __forceinline__ unsigned int scale2(unsigned int u, float s) {
  float lo = __uint_as_float(u << 16);
  float hi = __uint_as_float(u & 0xffff0000u);
  return pk_bf16(lo * s, hi * s);
}

// ---------------- K0: convert W_ih (192x1344 f32) to bf16
__global__ __launch_bounds__(256) void k0_convw(
    const float* __restrict__ W, unsigned short* __restrict__ Wbf) {
  const int ti = blockIdx.x*256 + threadIdx.x;
  const float4 v = ((const float4*)W)[ti];
  uint2 o;
  o.x = (unsigned int)f2bf(v.x) | ((unsigned int)f2bf(v.y) << 16);
  o.y = (unsigned int)f2bf(v.z) | ((unsigned int)f2bf(v.w) << 16);
  ((uint2*)Wbf)[ti] = o;
}

// ---------------- K1: fused GCN x2 via MFMA, linear padded LDS (unchanged, passing)
__global__ __launch_bounds__(256, 2) void k1_fused(
    const float* __restrict__ x, const float* __restrict__ A,
    const float* __restrict__ W1, const float* __restrict__ b1,
    const float* __restrict__ W2, const float* __restrict__ b2,
    const float* __restrict__ Wa,
    unsigned short* __restrict__ h2out, float* __restrict__ scorepart) {
  __shared__ unsigned short h1s[FB*32*72];   // 18 KB  [row][72]
  __shared__ unsigned short us[FB*64*40];    // 20 KB  us[f][h][40]
  __shared__ unsigned short w2s[64*72];      // 9 KB   [h][72]
  __shared__ unsigned short adjs[32*40];     // 2.5 KB [i][40]
  __shared__ unsigned short h2st[FB*NJ*72];  // 11.8 KB [f*21+i][72]
  __shared__ float afs[NJ*NJ];
  __shared__ float xs[4][64];
  __shared__ float ags[4][64];
  __shared__ float spred[4][NJ];

  const int tid = threadIdx.x;
  const int w = tid >> 6, l = tid & 63;
  const int q = l >> 4, r = l & 15;
  const int b = blockIdx.x >> 7, ch = blockIdx.x & 127;
  const int t0 = ch * FB;

  for (int i = tid; i < NJ*NJ; i += 256) afs[i] = A[i];
  for (int i = tid; i < 1024; i += 256) {
    const int ii = i >> 5, jj = i & 31;
    adjs[ii*40 + jj] = (ii < NJ && jj < NJ) ? f2bf(A[ii*NJ + jj]) : (unsigned short)0;
  }
  {
    const int h = tid & 63, qd = tid >> 6;
    const int g0 = qd * 16;
#pragma unroll
    for (int e = 0; e < 16; e += 2) {
      const float v0 = W2[h*64 + g0 + e], v1 = W2[h*64 + g0 + e + 1];
      ((unsigned int*)w2s)[h*36 + ((g0 + e) >> 1)] = pk_bf16(v0, v1);
    }
  }
#pragma unroll
  for (int j = NJ; j < 32; ++j)
    ((unsigned int*)h1s)[(w*32 + j)*36 + (l & 31)] = 0u;

  const float w1r0 = W1[l*3+0], w1r1 = W1[l*3+1], w1r2 = W1[l*3+2];
  const float b1h = b1[l];
  float b2v[4][4], wav[4][4];
#pragma unroll
  for (int mt = 0; mt < 4; ++mt)
#pragma unroll
    for (int rg = 0; rg < 4; ++rg) {
      const int h = mt*16 + q*4 + rg;
      b2v[mt][rg] = b2[h]; wav[mt][rg] = Wa[h];
    }
  __syncthreads();   // B0

  {
    const size_t fr = (size_t)(b*NT + t0 + w);
    if (l < NJ*NC) xs[w][l] = x[fr*(NJ*NC) + l];
    if (l < NJ*NC) {
      const int ji = l / 3, c = l - ji*3;
      float s = 0.f;
#pragma unroll
      for (int j = 0; j < NJ; ++j) s += afs[ji*NJ + j] * xs[w][j*3 + c];
      ags[w][l] = s;
    }
#pragma unroll
    for (int j = 0; j < NJ; ++j) {
      float v = b1h + w1r0*ags[w][j*3+0] + w1r1*ags[w][j*3+1] + w1r2*ags[w][j*3+2];
      v = fmaxf(v, 0.f);
      h1s[(w*32 + j)*72 + l] = f2bf(v);
    }
  }
  __syncthreads();   // B1

  bf16x8 bw[2][4];
#pragma unroll
  for (int ks = 0; ks < 2; ++ks)
#pragma unroll
    for (int nt = 0; nt < 4; ++nt)
      bw[ks][nt] = *(const bf16x8*)(&w2s[(nt*16 + r)*72 + (ks*4 + q)*8]);
  f32x4 acc1[2][4];
#pragma unroll
  for (int i = 0; i < 2; ++i)
#pragma unroll
    for (int j2 = 0; j2 < 4; ++j2) acc1[i][j2] = (f32x4)0.f;
#pragma unroll
  for (int mti = 0; mti < 2; ++mti) {
    const int row = (w*2 + mti)*16 + r;
#pragma unroll
    for (int ks = 0; ks < 2; ++ks) {
      const bf16x8 af = *(const bf16x8*)(&h1s[row*72 + (ks*4 + q)*8]);
#pragma unroll
      for (int nt = 0; nt < 4; ++nt)
        acc1[mti][nt] = __builtin_amdgcn_mfma_f32_16x16x32_bf16(af, bw[ks][nt], acc1[mti][nt], 0,0,0);
    }
  }
#pragma unroll
  for (int mti = 0; mti < 2; ++mti)
#pragma unroll
    for (int nt = 0; nt < 4; ++nt) {
      const int h = nt*16 + r;
#pragma unroll
      for (int rp = 0; rp < 2; ++rp) {
        const int jp = mti*16 + q*4 + rp*2;
        ((unsigned int*)us)[(w*64 + h)*20 + (jp >> 1)] =
            pk_bf16(acc1[mti][nt][rp*2], acc1[mti][nt][rp*2+1]);
      }
    }
  __syncthreads();   // B2

  bf16x8 badj[2];
#pragma unroll
  for (int nt = 0; nt < 2; ++nt)
    badj[nt] = *(const bf16x8*)(&adjs[(nt*16 + r)*40 + q*8]);
  f32x4 acc2[4][2];
#pragma unroll
  for (int i = 0; i < 4; ++i) { acc2[i][0] = (f32x4)0.f; acc2[i][1] = (f32x4)0.f; }
#pragma unroll
  for (int mt = 0; mt < 4; ++mt) {
    const int h = mt*16 + r;
    const bf16x8 af = *(const bf16x8*)(&us[(w*64 + h)*40 + q*8]);
#pragma unroll
    for (int nt = 0; nt < 2; ++nt)
      acc2[mt][nt] = __builtin_amdgcn_mfma_f32_16x16x32_bf16(af, badj[nt], acc2[mt][nt], 0,0,0);
  }
  float sp0 = 0.f, sp1 = 0.f;
#pragma unroll
  for (int nt = 0; nt < 2; ++nt) {
    const int i = nt*16 + r;
    if (i < NJ) {
#pragma unroll
      for (int mt = 0; mt < 4; ++mt)
#pragma unroll
        for (int rp = 0; rp < 2; ++rp) {
          const int h0 = mt*16 + q*4 + rp*2;
          const float v0 = fmaxf(acc2[mt][nt][rp*2]   + b2v[mt][rp*2],   0.f);
          const float v1 = fmaxf(acc2[mt][nt][rp*2+1] + b2v[mt][rp*2+1], 0.f);
          if (nt == 0) sp0 += v0*wav[mt][rp*2] + v1*wav[mt][rp*2+1];
          else         sp1 += v0*wav[mt][rp*2] + v1*wav[mt][rp*2+1];
          ((unsigned int*)h2st)[(w*NJ + i)*36 + (h0 >> 1)] = pk_bf16(v0, v1);
        }
    }
  }
  sp0 += __shfl_xor(sp0, 16); sp0 += __shfl_xor(sp0, 32);
  sp1 += __shfl_xor(sp1, 16); sp1 += __shfl_xor(sp1, 32);
  if (l < 16) spred[w][l] = sp0;
  if (l < 5)  spred[w][16 + l] = sp1;
  __syncthreads();   // B3

  if (tid < NJ)
    scorepart[((size_t)b*128 + ch)*NJ + tid] =
      spred[0][tid] + spred[1][tid] + spred[2][tid] + spred[3][tid];

  const size_t gbase = (size_t)(b*NT + t0) * JH;
  for (int cid = tid; cid < FB*NJ*8; cid += 256) {
    const int f = cid / (NJ*8), rem = cid - f*(NJ*8);
    const int i = rem >> 3, p = rem & 7;
    const uint4 v = *(const uint4*)(&h2st[(f*NJ + i)*72 + p*8]);
    *(uint4*)(&h2out[gbase + (size_t)f*JH + i*64 + p*8]) = v;
  }
}

// ---------------- K2: reduce score partials, softmax over joints
__global__ __launch_bounds__(64) void k2_attn(
    const float* __restrict__ scorepart, float* __restrict__ attn,
    float* __restrict__ out_attn) {
  __shared__ float ss[NJ];
  const int b = blockIdx.x, tid = threadIdx.x;
  if (tid < NJ) {
    float s = 0.f;
    for (int ch = 0; ch < 128; ++ch) s += scorepart[(b*128 + ch)*NJ + tid];
    ss[tid] = s * (1.0f/NT);
  }
  __syncthreads();
  float m = -1e30f;
  for (int j = 0; j < NJ; ++j) m = fmaxf(m, ss[j]);
  float sum = 0.f;
  for (int j = 0; j < NJ; ++j) sum += expf(ss[j] - m);
  if (tid < NJ) {
    float a = expf(ss[tid] - m) / sum;
    attn[b*NJ + tid] = a;
    out_attn[b*NJ + tid] = a;
  }
}

// ---------------- K3: xproj^T = (h2 * attn) @ W_ih.T + b_ih  -- MFMA bf16
// Output layout now [b][g][t] (t-major) so k4 can prefetch 4 steps as float4.
__global__ __launch_bounds__(256, 2) void k3_xproj_mfma(
    const unsigned short* __restrict__ h2, const unsigned short* __restrict__ Wbf,
    const float* __restrict__ b_ih, const float* __restrict__ attn,
    float* __restrict__ xproj) {
  __shared__ unsigned short Abuf[2][128*32];
  __shared__ unsigned short Bbuf[2][192*32];
  const int tid = threadIdx.x;
  const int w = tid >> 6, l = tid & 63;
  const int lq = l >> 4, lr = l & 15;
  const int blk = blockIdx.x;
  const int b = blk >> 2;
  const int t0 = (blk & 3) << 7;
  const int wm = w >> 1, wn = w & 1;

  const unsigned short* gA[2]; int ldsA[2];
#pragma unroll
  for (int i = 0; i < 2; ++i) {
    const int lc = tid*2 + i, rr = lc >> 2, j = lc & 3;
    gA[i] = h2 + (size_t)(b*NT + t0 + rr)*JH + j*8;
    ldsA[i] = rr*32 + ((j ^ ((rr>>1)&3)) << 3);
  }
  const unsigned short* gB[3]; int ldsB[3];
#pragma unroll
  for (int i = 0; i < 3; ++i) {
    const int lc = tid + 256*i, g = lc >> 2, j = lc & 3;
    gB[i] = Wbf + (size_t)g*JH + j*8;
    ldsB[i] = g*32 + ((j ^ ((g>>1)&3)) << 3);
  }
  int aoff[4], boff[6];
#pragma unroll
  for (int mt = 0; mt < 4; ++mt) {
    const int row = wm*64 + mt*16 + lr;
    aoff[mt] = row*32 + ((lq ^ ((row>>1)&3)) << 3);
  }
#pragma unroll
  for (int nt = 0; nt < 6; ++nt) {
    const int g = wn*96 + nt*16 + lr;
    boff[nt] = g*32 + ((lq ^ ((g>>1)&3)) << 3);
  }

  f32x4 acc[4][6];
#pragma unroll
  for (int mt = 0; mt < 4; ++mt)
#pragma unroll
    for (int nt = 0; nt < 6; ++nt) acc[mt][nt] = (f32x4)0.f;

  {
    const float s = attn[b*NJ + 0];
#pragma unroll
    for (int i = 0; i < 2; ++i)
      *(uint4*)(&Abuf[0][ldsA[i]]) = *(const uint4*)(gA[i]);
#pragma unroll
    for (int i = 0; i < 3; ++i) {
      uint4 v = *(const uint4*)(gB[i]);
      v.x = scale2(v.x, s); v.y = scale2(v.y, s);
      v.z = scale2(v.z, s); v.w = scale2(v.w, s);
      *(uint4*)(&Bbuf[0][ldsB[i]]) = v;
    }
  }
  __syncthreads();

  for (int ks = 0; ks < 42; ++ks) {
    const int cur = ks & 1;
    uint4 av0, av1, bv0, bv1, bv2;
    if (ks < 41) {
      const int kk = (ks+1)*32;
      av0 = *(const uint4*)(gA[0] + kk);
      av1 = *(const uint4*)(gA[1] + kk);
      bv0 = *(const uint4*)(gB[0] + kk);
      bv1 = *(const uint4*)(gB[1] + kk);
      bv2 = *(const uint4*)(gB[2] + kk);
    }
    bf16x8 af[4], bfr[6];
#pragma unroll
    for (int mt = 0; mt < 4; ++mt) af[mt] = *(const bf16x8*)(&Abuf[cur][aoff[mt]]);
#pragma unroll
    for (int nt = 0; nt < 6; ++nt) bfr[nt] = *(const bf16x8*)(&Bbuf[cur][boff[nt]]);
#pragma unroll
    for (int mt = 0; mt < 4; ++mt)
#pragma unroll
      for (int nt = 0; nt < 6; ++nt)
        acc[mt][nt] = __builtin_amdgcn_mfma_f32_16x16x32_bf16(af[mt], bfr[nt], acc[mt][nt], 0, 0, 0);
    if (ks < 41) {
      const float s = attn[b*NJ + ((ks+1) >> 1)];
      *(uint4*)(&Abuf[cur^1][ldsA[0]]) = av0;
      *(uint4*)(&Abuf[cur^1][ldsA[1]]) = av1;
      uint4 v;
      v = bv0; v.x = scale2(v.x, s); v.y = scale2(v.y, s); v.z = scale2(v.z, s); v.w = scale2(v.w, s);
      *(uint4*)(&Bbuf[cur^1][ldsB[0]]) = v;
      v = bv1; v.x = scale2(v.x, s); v.y = scale2(v.y, s); v.z = scale2(v.z, s); v.w = scale2(v.w, s);
      *(uint4*)(&Bbuf[cur^1][ldsB[1]]) = v;
      v = bv2; v.x = scale2(v.x, s); v.y = scale2(v.y, s); v.z = scale2(v.z, s); v.w = scale2(v.w, s);
      *(uint4*)(&Bbuf[cur^1][ldsB[2]]) = v;
    }
    __syncthreads();
  }

  // epilogue: bias + store as [b][g][t] float4 (4 consecutive t per acc)
  float bias[6];
#pragma unroll
  for (int nt = 0; nt < 6; ++nt) bias[nt] = b_ih[wn*96 + nt*16 + lr];
#pragma unroll
  for (int mt = 0; mt < 4; ++mt)
#pragma unroll
    for (int nt = 0; nt < 6; ++nt) {
      const int g = wn*96 + nt*16 + lr;
      const int trow = t0 + wm*64 + mt*16 + lq*4;
      float4 o;
      o.x = acc[mt][nt][0] + bias[nt];
      o.y = acc[mt][nt][1] + bias[nt];
      o.z = acc[mt][nt][2] + bias[nt];
      o.w = acc[mt][nt][3] + bias[nt];
      *(float4*)(&xproj[(size_t)(b*G3 + g)*NT + trow]) = o;
    }
}

// ---------------- K4: MFMA GRU. 16 batches/block, 8 blocks, 512 thr (8 waves).
// gh^T = Wg @ h^T per step: Wg = W_hh rows permuted to 4/channel (r,z,n,pad),
// M=256, K=64, N=16. Wave w owns m-tiles {2w,2w+1}; lane (q,r15) gets
// D rows 4ch..4ch+2 (ch=mt*4+q) for batch r15 -> gate math lane-local.
// h fp32 in regs; LDS operand bf16 hi+lo split (fp32-quality matvec).
// Ping-pong h buffers, 1 barrier/step; xproj[b][g][t] prefetched 4 steps.
__global__ __launch_bounds__(512, 1) void k4_gru_mfma(
    const float* __restrict__ xproj, const float* __restrict__ W_hh,
    const float* __restrict__ b_hh, float* __restrict__ hT) {
  __shared__ __align__(16) unsigned short hb[2][2][16*72];  // [buf][hi/lo][batch*72+ch]
  const int tid = threadIdx.x;
  const int w = tid >> 6, l = tid & 63, q = l >> 4, r15 = l & 15;
  const int b0 = blockIdx.x * 16;

  for (int i = tid; i < 2*2*16*72; i += 512) (&hb[0][0][0])[i] = 0;

  // A-frags (W_hh rows, bf16) + per-lane channel/bias
  bf16x8 afr[2][2];
  int chv[2]; float br_[2], bz_[2], bn_[2];
#pragma unroll
  for (int i = 0; i < 2; ++i) {
    const int mt = 2*w + i;
    const int row = mt*16 + r15;
    const int chs = row >> 2, gate = row & 3;
#pragma unroll
    for (int ks = 0; ks < 2; ++ks) {
      union { bf16x8 v; unsigned int u[4]; } tu;
      if (gate < 3) {
        const float* src = W_hh + (size_t)(gate*NH + chs)*NH + ks*32 + q*8;
        const float4 a = *(const float4*)(src);
        const float4 b = *(const float4*)(src + 4);
        tu.u[0] = pk_bf16(a.x, a.y); tu.u[1] = pk_bf16(a.z, a.w);
        tu.u[2] = pk_bf16(b.x, b.y); tu.u[3] = pk_bf16(b.z, b.w);
      } else {
        tu.u[0]=0u; tu.u[1]=0u; tu.u[2]=0u; tu.u[3]=0u;
      }
      afr[i][ks] = tu.v;
    }
    chv[i] = mt*4 + q;
    br_[i] = b_hh[chv[i]]; bz_[i] = b_hh[NH + chv[i]]; bn_[i] = b_hh[2*NH + chv[i]];
  }

  const float* xrow[2][3];
#pragma unroll
  for (int i = 0; i < 2; ++i)
#pragma unroll
    for (int e = 0; e < 3; ++e)
      xrow[i][e] = xproj + (size_t)((b0 + r15)*G3 + e*NH + chv[i]) * NT;

  f32x4 cur[2][3], nxt[2][3];
#pragma unroll
  for (int i = 0; i < 2; ++i)
#pragma unroll
    for (int e = 0; e < 3; ++e) cur[i][e] = *(const f32x4*)(xrow[i][e]);

  float hprev[2] = {0.f, 0.f};
  __syncthreads();

  for (int tg = 0; tg < NT; tg += 4) {
    if (tg + 4 < NT) {
#pragma unroll
      for (int i = 0; i < 2; ++i)
#pragma unroll
        for (int e = 0; e < 3; ++e) nxt[i][e] = *(const f32x4*)(xrow[i][e] + tg + 4);
    }
#pragma unroll
    for (int p = 0; p < 4; ++p) {
      const int rb = p & 1, wb = rb ^ 1;
      const bf16x8 bhi0 = *(const bf16x8*)(&hb[rb][0][r15*72 + q*8]);
      const bf16x8 bhi1 = *(const bf16x8*)(&hb[rb][0][r15*72 + 32 + q*8]);
      const bf16x8 blo0 = *(const bf16x8*)(&hb[rb][1][r15*72 + q*8]);
      const bf16x8 blo1 = *(const bf16x8*)(&hb[rb][1][r15*72 + 32 + q*8]);
#pragma unroll
      for (int i = 0; i < 2; ++i) {
        f32x4 acc = (f32x4)0.f;
        acc = __builtin_amdgcn_mfma_f32_16x16x32_bf16(afr[i][0], blo0, acc, 0,0,0);
        acc = __builtin_amdgcn_mfma_f32_16x16x32_bf16(afr[i][1], blo1, acc, 0,0,0);
        acc = __builtin_amdgcn_mfma_f32_16x16x32_bf16(afr[i][0], bhi0, acc, 0,0,0);
        acc = __builtin_amdgcn_mfma_f32_16x16x32_bf16(afr[i][1], bhi1, acc, 0,0,0);
        const float xr = cur[i][0][p], xz = cur[i][1][p], xn = cur[i][2][p];
        const float hr = acc[0] + br_[i];
        const float hz = acc[1] + bz_[i];
        const float hn = acc[2] + bn_[i];
        const float rr = __builtin_amdgcn_rcpf(1.f + __expf(-(xr + hr)));
        const float zz = __builtin_amdgcn_rcpf(1.f + __expf(-(xz + hz)));
        const float nx = xn + rr*hn;
        const float nn = 2.f*__builtin_amdgcn_rcpf(1.f + __expf(-2.f*nx)) - 1.f;
        const float h = (1.f - zz)*nn + zz*hprev[i];
        hprev[i] = h;
        const unsigned short hi16 = f2bf(h);
        const unsigned short lo16 = f2bf(h - bf2f(hi16));
        hb[wb][0][r15*72 + chv[i]] = hi16;
        hb[wb][1][r15*72 + chv[i]] = lo16;
      }
      __syncthreads();
    }
#pragma unroll
    for (int i = 0; i < 2; ++i)
#pragma unroll
      for (int e = 0; e < 3; ++e) cur[i][e] = nxt[i][e];
  }

#pragma unroll
  for (int i = 0; i < 2; ++i)
    hT[(size_t)(b0 + r15)*NH + chv[i]] = hprev[i];
}

// ---------------- K5: head
__global__ __launch_bounds__(256) void k5_head(
    const float* __restrict__ hT, const float* __restrict__ W_head,
    const float* __restrict__ b_head, float* __restrict__ out) {
  const int idx = blockIdx.x*256 + threadIdx.x;
  if (idx >= NB*63) return;
  const int b = idx / 63, rr = idx % 63;
  const float* hv = hT + b*NH;
  const float* wr = W_head + rr*NH;
  float acc = b_head[rr];
#pragma unroll
  for (int k = 0; k < NH; ++k) acc += hv[k]*wr[k];
  out[idx] = acc;
}

extern "C" void kernel_launch(void* const* d_in, const int* in_sizes, int n_in,
                              void* d_out, int out_size, void* d_ws, size_t ws_size,
                              hipStream_t stream) {
  const float* x      = (const float*)d_in[0];
  const float* A      = (const float*)d_in[1];
  const float* W1     = (const float*)d_in[2];
  const float* b1     = (const float*)d_in[3];
  const float* W2     = (const float*)d_in[4];
  const float* b2     = (const float*)d_in[5];
  const float* Wa     = (const float*)d_in[6];
  // d_in[7] = ba : softmax-invariant, unused
  const float* W_ih   = (const float*)d_in[8];
  const float* b_ih   = (const float*)d_in[9];
  const float* W_hh   = (const float*)d_in[10];
  const float* b_hh   = (const float*)d_in[11];
  const float* W_head = (const float*)d_in[12];
  const float* b_head = (const float*)d_in[13];
  float* out = (float*)d_out;

  char* ws = (char*)d_ws;
  size_t off = 0;
  unsigned short* h2 = (unsigned short*)(ws + off); off += (size_t)NB*NT*JH*2;   // 176 MB
  float* scorepart   = (float*)(ws + off);          off += (size_t)NB*128*NJ*4;  // 1.38 MB
  float* attn        = (float*)(ws + off);          off += (size_t)NB*NJ*4;
  off = (off + 15) & ~(size_t)15;
  float* xproj       = (float*)(ws + off);          off += (size_t)NB*NT*G3*4;   // 50 MB, [b][g][t]
  float* hT          = (float*)(ws + off);          off += (size_t)NB*NH*4;
  off = (off + 15) & ~(size_t)15;
  unsigned short* Wbf = (unsigned short*)(ws + off); off += (size_t)G3*JH*2;     // 516 KB

  k0_convw<<<dim3(252),       256, 0, stream>>>(W_ih, Wbf);
  k1_fused<<<dim3(NB*128),    256, 0, stream>>>(x, A, W1, b1, W2, b2, Wa, h2, scorepart);
  k2_attn<<<dim3(NB),          64, 0, stream>>>(scorepart, attn, out + OUT0);
  k3_xproj_mfma<<<dim3(512),  256, 0, stream>>>(h2, Wbf, b_ih, attn, xproj);
  k4_gru_mfma<<<dim3(8),      512, 0, stream>>>(xproj, W_hh, b_hh, hT);
  k5_head<<<dim3((NB*63 + 255)/256), 256, 0, stream>>>(hT, W_head, b_head, out);
}

// Round 7
// 561.625 us; speedup vs baseline: 1.1054x; 1.0773x over previous
//
#include <hip/hip_runtime.h>
#include <cstdint>
#include <cstddef>

#define NB 128
#define NT 512
#define NJ 21
#define NC 3
#define NH 64
#define JH 1344   // NJ*NH
#define G3 192    // 3*NH
#define OUT0 (NB*NJ*NC) // 8064
#define FB 4      // frames per k1 block (one per wave)

typedef __attribute__((ext_vector_type(8))) __bf16 bf16x8;
typedef __attribute__((ext_vector_type(4))) float f32x4;

__device__ __forceinline__ float bf2f(unsigned short u) {
  union { unsigned int i; float f; } v; v.i = ((unsigned int)u) << 16; return v.f;
}
__device__ __forceinline__ unsigned short f2bf(float f) {
  union { float f; unsigned int i; } v; v.f = f;
  unsigned int x = v.i;
  unsigned int lsb = (x >> 16) & 1u;
  x += 0x7fffu + lsb;
  return (unsigned short)(x >> 16);
}
__device__ __forceinline__ unsigned int pk_bf16(float lo, float hi) {
  unsigned int r;
  asm("v_cvt_pk_bf16_f32 %0, %1, %2" : "=v"(r) : "v"(lo), "v"(hi));
  return r;
}
__device__ __forceinline__ unsigned int scale2(unsigned int u, float s) {
  float lo = __uint_as_float(u << 16);
  float hi = __uint_as_float(u & 0xffff0000u);
  return pk_bf16(lo * s, hi * s);
}

// ---------------- K0: convert W_ih (192x1344 f32) to bf16
__global__ __launch_bounds__(256) void k0_convw(
    const float* __restrict__ W, unsigned short* __restrict__ Wbf) {
  const int ti = blockIdx.x*256 + threadIdx.x;
  const float4 v = ((const float4*)W)[ti];
  uint2 o;
  o.x = (unsigned int)f2bf(v.x) | ((unsigned int)f2bf(v.y) << 16);
  o.y = (unsigned int)f2bf(v.z) | ((unsigned int)f2bf(v.w) << 16);
  ((uint2*)Wbf)[ti] = o;
}

// ---------------- K1: fused GCN x2 via MFMA, linear padded LDS (unchanged, passing)
__global__ __launch_bounds__(256, 2) void k1_fused(
    const float* __restrict__ x, const float* __restrict__ A,
    const float* __restrict__ W1, const float* __restrict__ b1,
    const float* __restrict__ W2, const float* __restrict__ b2,
    const float* __restrict__ Wa,
    unsigned short* __restrict__ h2out, float* __restrict__ scorepart) {
  __shared__ unsigned short h1s[FB*32*72];   // 18 KB  [row][72]
  __shared__ unsigned short us[FB*64*40];    // 20 KB  us[f][h][40]
  __shared__ unsigned short w2s[64*72];      // 9 KB   [h][72]
  __shared__ unsigned short adjs[32*40];     // 2.5 KB [i][40]
  __shared__ unsigned short h2st[FB*NJ*72];  // 11.8 KB [f*21+i][72]
  __shared__ float afs[NJ*NJ];
  __shared__ float xs[4][64];
  __shared__ float ags[4][64];
  __shared__ float spred[4][NJ];

  const int tid = threadIdx.x;
  const int w = tid >> 6, l = tid & 63;
  const int q = l >> 4, r = l & 15;
  const int b = blockIdx.x >> 7, ch = blockIdx.x & 127;
  const int t0 = ch * FB;

  for (int i = tid; i < NJ*NJ; i += 256) afs[i] = A[i];
  for (int i = tid; i < 1024; i += 256) {
    const int ii = i >> 5, jj = i & 31;
    adjs[ii*40 + jj] = (ii < NJ && jj < NJ) ? f2bf(A[ii*NJ + jj]) : (unsigned short)0;
  }
  {
    const int h = tid & 63, qd = tid >> 6;
    const int g0 = qd * 16;
#pragma unroll
    for (int e = 0; e < 16; e += 2) {
      const float v0 = W2[h*64 + g0 + e], v1 = W2[h*64 + g0 + e + 1];
      ((unsigned int*)w2s)[h*36 + ((g0 + e) >> 1)] = pk_bf16(v0, v1);
    }
  }
#pragma unroll
  for (int j = NJ; j < 32; ++j)
    ((unsigned int*)h1s)[(w*32 + j)*36 + (l & 31)] = 0u;

  const float w1r0 = W1[l*3+0], w1r1 = W1[l*3+1], w1r2 = W1[l*3+2];
  const float b1h = b1[l];
  float b2v[4][4], wav[4][4];
#pragma unroll
  for (int mt = 0; mt < 4; ++mt)
#pragma unroll
    for (int rg = 0; rg < 4; ++rg) {
      const int h = mt*16 + q*4 + rg;
      b2v[mt][rg] = b2[h]; wav[mt][rg] = Wa[h];
    }
  __syncthreads();   // B0

  {
    const size_t fr = (size_t)(b*NT + t0 + w);
    if (l < NJ*NC) xs[w][l] = x[fr*(NJ*NC) + l];
    if (l < NJ*NC) {
      const int ji = l / 3, c = l - ji*3;
      float s = 0.f;
#pragma unroll
      for (int j = 0; j < NJ; ++j) s += afs[ji*NJ + j] * xs[w][j*3 + c];
      ags[w][l] = s;
    }
#pragma unroll
    for (int j = 0; j < NJ; ++j) {
      float v = b1h + w1r0*ags[w][j*3+0] + w1r1*ags[w][j*3+1] + w1r2*ags[w][j*3+2];
      v = fmaxf(v, 0.f);
      h1s[(w*32 + j)*72 + l] = f2bf(v);
    }
  }
  __syncthreads();   // B1

  bf16x8 bw[2][4];
#pragma unroll
  for (int ks = 0; ks < 2; ++ks)
#pragma unroll
    for (int nt = 0; nt < 4; ++nt)
      bw[ks][nt] = *(const bf16x8*)(&w2s[(nt*16 + r)*72 + (ks*4 + q)*8]);
  f32x4 acc1[2][4];
#pragma unroll
  for (int i = 0; i < 2; ++i)
#pragma unroll
    for (int j2 = 0; j2 < 4; ++j2) acc1[i][j2] = (f32x4)0.f;
#pragma unroll
  for (int mti = 0; mti < 2; ++mti) {
    const int row = (w*2 + mti)*16 + r;
#pragma unroll
    for (int ks = 0; ks < 2; ++ks) {
      const bf16x8 af = *(const bf16x8*)(&h1s[row*72 + (ks*4 + q)*8]);
#pragma unroll
      for (int nt = 0; nt < 4; ++nt)
        acc1[mti][nt] = __builtin_amdgcn_mfma_f32_16x16x32_bf16(af, bw[ks][nt], acc1[mti][nt], 0,0,0);
    }
  }
#pragma unroll
  for (int mti = 0; mti < 2; ++mti)
#pragma unroll
    for (int nt = 0; nt < 4; ++nt) {
      const int h = nt*16 + r;
#pragma unroll
      for (int rp = 0; rp < 2; ++rp) {
        const int jp = mti*16 + q*4 + rp*2;
        ((unsigned int*)us)[(w*64 + h)*20 + (jp >> 1)] =
            pk_bf16(acc1[mti][nt][rp*2], acc1[mti][nt][rp*2+1]);
      }
    }
  __syncthreads();   // B2

  bf16x8 badj[2];
#pragma unroll
  for (int nt = 0; nt < 2; ++nt)
    badj[nt] = *(const bf16x8*)(&adjs[(nt*16 + r)*40 + q*8]);
  f32x4 acc2[4][2];
#pragma unroll
  for (int i = 0; i < 4; ++i) { acc2[i][0] = (f32x4)0.f; acc2[i][1] = (f32x4)0.f; }
#pragma unroll
  for (int mt = 0; mt < 4; ++mt) {
    const int h = mt*16 + r;
    const bf16x8 af = *(const bf16x8*)(&us[(w*64 + h)*40 + q*8]);
#pragma unroll
    for (int nt = 0; nt < 2; ++nt)
      acc2[mt][nt] = __builtin_amdgcn_mfma_f32_16x16x32_bf16(af, badj[nt], acc2[mt][nt], 0,0,0);
  }
  float sp0 = 0.f, sp1 = 0.f;
#pragma unroll
  for (int nt = 0; nt < 2; ++nt) {
    const int i = nt*16 + r;
    if (i < NJ) {
#pragma unroll
      for (int mt = 0; mt < 4; ++mt)
#pragma unroll
        for (int rp = 0; rp < 2; ++rp) {
          const int h0 = mt*16 + q*4 + rp*2;
          const float v0 = fmaxf(acc2[mt][nt][rp*2]   + b2v[mt][rp*2],   0.f);
          const float v1 = fmaxf(acc2[mt][nt][rp*2+1] + b2v[mt][rp*2+1], 0.f);
          if (nt == 0) sp0 += v0*wav[mt][rp*2] + v1*wav[mt][rp*2+1];
          else         sp1 += v0*wav[mt][rp*2] + v1*wav[mt][rp*2+1];
          ((unsigned int*)h2st)[(w*NJ + i)*36 + (h0 >> 1)] = pk_bf16(v0, v1);
        }
    }
  }
  sp0 += __shfl_xor(sp0, 16); sp0 += __shfl_xor(sp0, 32);
  sp1 += __shfl_xor(sp1, 16); sp1 += __shfl_xor(sp1, 32);
  if (l < 16) spred[w][l] = sp0;
  if (l < 5)  spred[w][16 + l] = sp1;
  __syncthreads();   // B3

  if (tid < NJ)
    scorepart[((size_t)b*128 + ch)*NJ + tid] =
      spred[0][tid] + spred[1][tid] + spred[2][tid] + spred[3][tid];

  const size_t gbase = (size_t)(b*NT + t0) * JH;
  for (int cid = tid; cid < FB*NJ*8; cid += 256) {
    const int f = cid / (NJ*8), rem = cid - f*(NJ*8);
    const int i = rem >> 3, p = rem & 7;
    const uint4 v = *(const uint4*)(&h2st[(f*NJ + i)*72 + p*8]);
    *(uint4*)(&h2out[gbase + (size_t)f*JH + i*64 + p*8]) = v;
  }
}

// ---------------- K2: reduce score partials, softmax over joints
__global__ __launch_bounds__(64) void k2_attn(
    const float* __restrict__ scorepart, float* __restrict__ attn,
    float* __restrict__ out_attn) {
  __shared__ float ss[NJ];
  const int b = blockIdx.x, tid = threadIdx.x;
  if (tid < NJ) {
    float s = 0.f;
    for (int ch = 0; ch < 128; ++ch) s += scorepart[(b*128 + ch)*NJ + tid];
    ss[tid] = s * (1.0f/NT);
  }
  __syncthreads();
  float m = -1e30f;
  for (int j = 0; j < NJ; ++j) m = fmaxf(m, ss[j]);
  float sum = 0.f;
  for (int j = 0; j < NJ; ++j) sum += expf(ss[j] - m);
  if (tid < NJ) {
    float a = expf(ss[tid] - m) / sum;
    attn[b*NJ + tid] = a;
    out_attn[b*NJ + tid] = a;
  }
}

// ---------------- K3: xproj^T = (h2 * attn) @ W_ih.T + b_ih  -- MFMA bf16
// Output layout [b][g][t] (t-major) so k4 can prefetch 4 steps as float4.
__global__ __launch_bounds__(256, 2) void k3_xproj_mfma(
    const unsigned short* __restrict__ h2, const unsigned short* __restrict__ Wbf,
    const float* __restrict__ b_ih, const float* __restrict__ attn,
    float* __restrict__ xproj) {
  __shared__ unsigned short Abuf[2][128*32];
  __shared__ unsigned short Bbuf[2][192*32];
  const int tid = threadIdx.x;
  const int w = tid >> 6, l = tid & 63;
  const int lq = l >> 4, lr = l & 15;
  const int blk = blockIdx.x;
  const int b = blk >> 2;
  const int t0 = (blk & 3) << 7;
  const int wm = w >> 1, wn = w & 1;

  const unsigned short* gA[2]; int ldsA[2];
#pragma unroll
  for (int i = 0; i < 2; ++i) {
    const int lc = tid*2 + i, rr = lc >> 2, j = lc & 3;
    gA[i] = h2 + (size_t)(b*NT + t0 + rr)*JH + j*8;
    ldsA[i] = rr*32 + ((j ^ ((rr>>1)&3)) << 3);
  }
  const unsigned short* gB[3]; int ldsB[3];
#pragma unroll
  for (int i = 0; i < 3; ++i) {
    const int lc = tid + 256*i, g = lc >> 2, j = lc & 3;
    gB[i] = Wbf + (size_t)g*JH + j*8;
    ldsB[i] = g*32 + ((j ^ ((g>>1)&3)) << 3);
  }
  int aoff[4], boff[6];
#pragma unroll
  for (int mt = 0; mt < 4; ++mt) {
    const int row = wm*64 + mt*16 + lr;
    aoff[mt] = row*32 + ((lq ^ ((row>>1)&3)) << 3);
  }
#pragma unroll
  for (int nt = 0; nt < 6; ++nt) {
    const int g = wn*96 + nt*16 + lr;
    boff[nt] = g*32 + ((lq ^ ((g>>1)&3)) << 3);
  }

  f32x4 acc[4][6];
#pragma unroll
  for (int mt = 0; mt < 4; ++mt)
#pragma unroll
    for (int nt = 0; nt < 6; ++nt) acc[mt][nt] = (f32x4)0.f;

  {
    const float s = attn[b*NJ + 0];
#pragma unroll
    for (int i = 0; i < 2; ++i)
      *(uint4*)(&Abuf[0][ldsA[i]]) = *(const uint4*)(gA[i]);
#pragma unroll
    for (int i = 0; i < 3; ++i) {
      uint4 v = *(const uint4*)(gB[i]);
      v.x = scale2(v.x, s); v.y = scale2(v.y, s);
      v.z = scale2(v.z, s); v.w = scale2(v.w, s);
      *(uint4*)(&Bbuf[0][ldsB[i]]) = v;
    }
  }
  __syncthreads();

  for (int ks = 0; ks < 42; ++ks) {
    const int cur = ks & 1;
    uint4 av0, av1, bv0, bv1, bv2;
    if (ks < 41) {
      const int kk = (ks+1)*32;
      av0 = *(const uint4*)(gA[0] + kk);
      av1 = *(const uint4*)(gA[1] + kk);
      bv0 = *(const uint4*)(gB[0] + kk);
      bv1 = *(const uint4*)(gB[1] + kk);
      bv2 = *(const uint4*)(gB[2] + kk);
    }
    bf16x8 af[4], bfr[6];
#pragma unroll
    for (int mt = 0; mt < 4; ++mt) af[mt] = *(const bf16x8*)(&Abuf[cur][aoff[mt]]);
#pragma unroll
    for (int nt = 0; nt < 6; ++nt) bfr[nt] = *(const bf16x8*)(&Bbuf[cur][boff[nt]]);
#pragma unroll
    for (int mt = 0; mt < 4; ++mt)
#pragma unroll
      for (int nt = 0; nt < 6; ++nt)
        acc[mt][nt] = __builtin_amdgcn_mfma_f32_16x16x32_bf16(af[mt], bfr[nt], acc[mt][nt], 0, 0, 0);
    if (ks < 41) {
      const float s = attn[b*NJ + ((ks+1) >> 1)];
      *(uint4*)(&Abuf[cur^1][ldsA[0]]) = av0;
      *(uint4*)(&Abuf[cur^1][ldsA[1]]) = av1;
      uint4 v;
      v = bv0; v.x = scale2(v.x, s); v.y = scale2(v.y, s); v.z = scale2(v.z, s); v.w = scale2(v.w, s);
      *(uint4*)(&Bbuf[cur^1][ldsB[0]]) = v;
      v = bv1; v.x = scale2(v.x, s); v.y = scale2(v.y, s); v.z = scale2(v.z, s); v.w = scale2(v.w, s);
      *(uint4*)(&Bbuf[cur^1][ldsB[1]]) = v;
      v = bv2; v.x = scale2(v.x, s); v.y = scale2(v.y, s); v.z = scale2(v.z, s); v.w = scale2(v.w, s);
      *(uint4*)(&Bbuf[cur^1][ldsB[2]]) = v;
    }
    __syncthreads();
  }

  float bias[6];
#pragma unroll
  for (int nt = 0; nt < 6; ++nt) bias[nt] = b_ih[wn*96 + nt*16 + lr];
#pragma unroll
  for (int mt = 0; mt < 4; ++mt)
#pragma unroll
    for (int nt = 0; nt < 6; ++nt) {
      const int g = wn*96 + nt*16 + lr;
      const int trow = t0 + wm*64 + mt*16 + lq*4;
      float4 o;
      o.x = acc[mt][nt][0] + bias[nt];
      o.y = acc[mt][nt][1] + bias[nt];
      o.z = acc[mt][nt][2] + bias[nt];
      o.w = acc[mt][nt][3] + bias[nt];
      *(float4*)(&xproj[(size_t)(b*G3 + g)*NT + trow]) = o;
    }
}

// ---------------- K4: MFMA GRU v3. 16 batches/block, 8 blocks, 512 thr/8 waves.
// Wg rows permuted so ch(mt,q) = 8*(mt>>1) + 2q + (mt&1): lane (w,q,r15) owns
// ADJACENT channels {8w+2q, 8w+2q+1} (i=0,1) for batch r15 -> h writeback is
// ONE packed ds_write_b32 at dword r15*36 + 4w+q (2 lanes/bank = free).
// h carried fp32 in regs; LDS operand plain bf16 (no hi/lo). 4 MFMAs/step as
// two independent 2-chains. One barrier/step; xproj [b][g][t] prefetched 4 deep.
__global__ __launch_bounds__(512, 1) void k4_gru_mfma(
    const float* __restrict__ xproj, const float* __restrict__ W_hh,
    const float* __restrict__ b_hh, float* __restrict__ hT) {
  __shared__ __align__(16) unsigned short hb[2][16*72];  // [buf][batch*72 + ch]
  const int tid = threadIdx.x;
  const int w = tid >> 6, l = tid & 63, q = l >> 4, r15 = l & 15;
  const int b0 = blockIdx.x * 16;

  for (int i = tid; i < 2*16*36; i += 512) ((unsigned int*)hb)[i] = 0u;

  // A-frags: Wg row r_glob = mt*16 + (row-in-tile); row r of tile mt maps to
  // (ch = 8*(mt>>1) + 2*(r>>2) + (mt&1), gate = r&3). A-frag: lane (q,r15)
  // holds A[row=r15][k=q*8+e+32ks].
  bf16x8 afr[2][2];
  int chv[2]; float br_[2], bz_[2], bn_[2];
#pragma unroll
  for (int i = 0; i < 2; ++i) {
    const int mt = 2*w + i;
    const int gate = r15 & 3;
    const int cha = 8*(mt >> 1) + 2*(r15 >> 2) + (mt & 1);  // A-side channel
#pragma unroll
    for (int ks = 0; ks < 2; ++ks) {
      union { bf16x8 v; unsigned int u[4]; } tu;
      if (gate < 3) {
        const float* src = W_hh + (size_t)(gate*NH + cha)*NH + ks*32 + q*8;
        const float4 a = *(const float4*)(src);
        const float4 b = *(const float4*)(src + 4);
        tu.u[0] = pk_bf16(a.x, a.y); tu.u[1] = pk_bf16(a.z, a.w);
        tu.u[2] = pk_bf16(b.x, b.y); tu.u[3] = pk_bf16(b.z, b.w);
      } else {
        tu.u[0]=0u; tu.u[1]=0u; tu.u[2]=0u; tu.u[3]=0u;
      }
      afr[i][ks] = tu.v;
    }
    chv[i] = 8*w + 2*q + i;   // D-side channel this lane owns
    br_[i] = b_hh[chv[i]]; bz_[i] = b_hh[NH + chv[i]]; bn_[i] = b_hh[2*NH + chv[i]];
  }

  const float* xrow[2][3];
#pragma unroll
  for (int i = 0; i < 2; ++i)
#pragma unroll
    for (int e = 0; e < 3; ++e)
      xrow[i][e] = xproj + (size_t)((b0 + r15)*G3 + e*NH + chv[i]) * NT;

  f32x4 cur[2][3], nxt[2][3];
#pragma unroll
  for (int i = 0; i < 2; ++i)
#pragma unroll
    for (int e = 0; e < 3; ++e) cur[i][e] = *(const f32x4*)(xrow[i][e]);

  float hprev[2] = {0.f, 0.f};
  __syncthreads();

  for (int tg = 0; tg < NT; tg += 4) {
    if (tg + 4 < NT) {
#pragma unroll
      for (int i = 0; i < 2; ++i)
#pragma unroll
        for (int e = 0; e < 3; ++e) nxt[i][e] = *(const f32x4*)(xrow[i][e] + tg + 4);
    }
#pragma unroll
    for (int p = 0; p < 4; ++p) {
      const int rb = p & 1, wb = rb ^ 1;
      const bf16x8 bh0 = *(const bf16x8*)(&hb[rb][r15*72 + q*8]);
      const bf16x8 bh1 = *(const bf16x8*)(&hb[rb][r15*72 + 32 + q*8]);
      f32x4 acc[2];
      acc[0] = (f32x4)0.f; acc[1] = (f32x4)0.f;
      acc[0] = __builtin_amdgcn_mfma_f32_16x16x32_bf16(afr[0][0], bh0, acc[0], 0,0,0);
      acc[1] = __builtin_amdgcn_mfma_f32_16x16x32_bf16(afr[1][0], bh0, acc[1], 0,0,0);
      acc[0] = __builtin_amdgcn_mfma_f32_16x16x32_bf16(afr[0][1], bh1, acc[0], 0,0,0);
      acc[1] = __builtin_amdgcn_mfma_f32_16x16x32_bf16(afr[1][1], bh1, acc[1], 0,0,0);
      float hnew[2];
#pragma unroll
      for (int i = 0; i < 2; ++i) {
        const float xr = cur[i][0][p], xz = cur[i][1][p], xn = cur[i][2][p];
        const float hr = acc[i][0] + br_[i];
        const float hz = acc[i][1] + bz_[i];
        const float hn = acc[i][2] + bn_[i];
        const float rr = __builtin_amdgcn_rcpf(1.f + __expf(-(xr + hr)));
        const float zz = __builtin_amdgcn_rcpf(1.f + __expf(-(xz + hz)));
        const float nx = xn + rr*hn;
        const float nn = 2.f*__builtin_amdgcn_rcpf(1.f + __expf(-2.f*nx)) - 1.f;
        hnew[i] = (1.f - zz)*nn + zz*hprev[i];
        hprev[i] = hnew[i];
      }
      ((unsigned int*)&hb[wb][0])[r15*36 + 4*w + q] = pk_bf16(hnew[0], hnew[1]);
      __syncthreads();
    }
#pragma unroll
    for (int i = 0; i < 2; ++i)
#pragma unroll
      for (int e = 0; e < 3; ++e) cur[i][e] = nxt[i][e];
  }

#pragma unroll
  for (int i = 0; i < 2; ++i)
    hT[(size_t)(b0 + r15)*NH + chv[i]] = hprev[i];
}

// ---------------- K5: head
__global__ __launch_bounds__(256) void k5_head(
    const float* __restrict__ hT, const float* __restrict__ W_head,
    const float* __restrict__ b_head, float* __restrict__ out) {
  const int idx = blockIdx.x*256 + threadIdx.x;
  if (idx >= NB*63) return;
  const int b = idx / 63, rr = idx % 63;
  const float* hv = hT + b*NH;
  const float* wr = W_head + rr*NH;
  float acc = b_head[rr];
#pragma unroll
  for (int k = 0; k < NH; ++k) acc += hv[k]*wr[k];
  out[idx] = acc;
}

extern "C" void kernel_launch(void* const* d_in, const int* in_sizes, int n_in,
                              void* d_out, int out_size, void* d_ws, size_t ws_size,
                              hipStream_t stream) {
  const float* x      = (const float*)d_in[0];
  const float* A      = (const float*)d_in[1];
  const float* W1     = (const float*)d_in[2];
  const float* b1     = (const float*)d_in[3];
  const float* W2     = (const float*)d_in[4];
  const float* b2     = (const float*)d_in[5];
  const float* Wa     = (const float*)d_in[6];
  // d_in[7] = ba : softmax-invariant, unused
  const float* W_ih   = (const float*)d_in[8];
  const float* b_ih   = (const float*)d_in[9];
  const float* W_hh   = (const float*)d_in[10];
  const float* b_hh   = (const float*)d_in[11];
  const float* W_head = (const float*)d_in[12];
  const float* b_head = (const float*)d_in[13];
  float* out = (float*)d_out;

  char* ws = (char*)d_ws;
  size_t off = 0;
  unsigned short* h2 = (unsigned short*)(ws + off); off += (size_t)NB*NT*JH*2;   // 176 MB
  float* scorepart   = (float*)(ws + off);          off += (size_t)NB*128*NJ*4;  // 1.38 MB
  float* attn        = (float*)(ws + off);          off += (size_t)NB*NJ*4;
  off = (off + 15) & ~(size_t)15;
  float* xproj       = (float*)(ws + off);          off += (size_t)NB*NT*G3*4;   // 50 MB, [b][g][t]
  float* hT          = (float*)(ws + off);          off += (size_t)NB*NH*4;
  off = (off + 15) & ~(size_t)15;
  unsigned short* Wbf = (unsigned short*)(ws + off); off += (size_t)G3*JH*2;     // 516 KB

  k0_convw<<<dim3(252),       256, 0, stream>>>(W_ih, Wbf);
  k1_fused<<<dim3(NB*128),    256, 0, stream>>>(x, A, W1, b1, W2, b2, Wa, h2, scorepart);
  k2_attn<<<dim3(NB),          64, 0, stream>>>(scorepart, attn, out + OUT0);
  k3_xproj_mfma<<<dim3(512),  256, 0, stream>>>(h2, Wbf, b_ih, attn, xproj);
  k4_gru_mfma<<<dim3(8),      512, 0, stream>>>(xproj, W_hh, b_hh, hT);
  k5_head<<<dim3((NB*63 + 255)/256), 256, 0, stream>>>(hT, W_head, b_head, out);
}

// Round 8
// 508.088 us; speedup vs baseline: 1.2219x; 1.1054x over previous
//
#include <hip/hip_runtime.h>
#include <cstdint>
#include <cstddef>

#define NB 128
#define NT 512
#define NJ 21
#define NC 3
#define NH 64
#define JH 1344   // NJ*NH
#define G3 192    // 3*NH
#define OUT0 (NB*NJ*NC) // 8064
#define FB 4      // frames per k1 block (one per wave)

typedef __attribute__((ext_vector_type(8))) __bf16 bf16x8;
typedef __attribute__((ext_vector_type(4))) float f32x4;

__device__ __forceinline__ float bf2f(unsigned short u) {
  union { unsigned int i; float f; } v; v.i = ((unsigned int)u) << 16; return v.f;
}
__device__ __forceinline__ unsigned short f2bf(float f) {
  union { float f; unsigned int i; } v; v.f = f;
  unsigned int x = v.i;
  unsigned int lsb = (x >> 16) & 1u;
  x += 0x7fffu + lsb;
  return (unsigned short)(x >> 16);
}
__device__ __forceinline__ unsigned int pk_bf16(float lo, float hi) {
  unsigned int r;
  asm("v_cvt_pk_bf16_f32 %0, %1, %2" : "=v"(r) : "v"(lo), "v"(hi));
  return r;
}
__device__ __forceinline__ unsigned int scale2(unsigned int u, float s) {
  float lo = __uint_as_float(u << 16);
  float hi = __uint_as_float(u & 0xffff0000u);
  return pk_bf16(lo * s, hi * s);
}

// ---------------- K0: convert W_ih (192x1344 f32) to bf16
__global__ __launch_bounds__(256) void k0_convw(
    const float* __restrict__ W, unsigned short* __restrict__ Wbf) {
  const int ti = blockIdx.x*256 + threadIdx.x;
  const float4 v = ((const float4*)W)[ti];
  uint2 o;
  o.x = (unsigned int)f2bf(v.x) | ((unsigned int)f2bf(v.y) << 16);
  o.y = (unsigned int)f2bf(v.z) | ((unsigned int)f2bf(v.w) << 16);
  ((uint2*)Wbf)[ti] = o;
}

// ---------------- K1: fused GCN x2 via MFMA, linear padded LDS (unchanged, passing)
__global__ __launch_bounds__(256, 2) void k1_fused(
    const float* __restrict__ x, const float* __restrict__ A,
    const float* __restrict__ W1, const float* __restrict__ b1,
    const float* __restrict__ W2, const float* __restrict__ b2,
    const float* __restrict__ Wa,
    unsigned short* __restrict__ h2out, float* __restrict__ scorepart) {
  __shared__ unsigned short h1s[FB*32*72];   // 18 KB  [row][72]
  __shared__ unsigned short us[FB*64*40];    // 20 KB  us[f][h][40]
  __shared__ unsigned short w2s[64*72];      // 9 KB   [h][72]
  __shared__ unsigned short adjs[32*40];     // 2.5 KB [i][40]
  __shared__ unsigned short h2st[FB*NJ*72];  // 11.8 KB [f*21+i][72]
  __shared__ float afs[NJ*NJ];
  __shared__ float xs[4][64];
  __shared__ float ags[4][64];
  __shared__ float spred[4][NJ];

  const int tid = threadIdx.x;
  const int w = tid >> 6, l = tid & 63;
  const int q = l >> 4, r = l & 15;
  const int b = blockIdx.x >> 7, ch = blockIdx.x & 127;
  const int t0 = ch * FB;

  for (int i = tid; i < NJ*NJ; i += 256) afs[i] = A[i];
  for (int i = tid; i < 1024; i += 256) {
    const int ii = i >> 5, jj = i & 31;
    adjs[ii*40 + jj] = (ii < NJ && jj < NJ) ? f2bf(A[ii*NJ + jj]) : (unsigned short)0;
  }
  {
    const int h = tid & 63, qd = tid >> 6;
    const int g0 = qd * 16;
#pragma unroll
    for (int e = 0; e < 16; e += 2) {
      const float v0 = W2[h*64 + g0 + e], v1 = W2[h*64 + g0 + e + 1];
      ((unsigned int*)w2s)[h*36 + ((g0 + e) >> 1)] = pk_bf16(v0, v1);
    }
  }
#pragma unroll
  for (int j = NJ; j < 32; ++j)
    ((unsigned int*)h1s)[(w*32 + j)*36 + (l & 31)] = 0u;

  const float w1r0 = W1[l*3+0], w1r1 = W1[l*3+1], w1r2 = W1[l*3+2];
  const float b1h = b1[l];
  float b2v[4][4], wav[4][4];
#pragma unroll
  for (int mt = 0; mt < 4; ++mt)
#pragma unroll
    for (int rg = 0; rg < 4; ++rg) {
      const int h = mt*16 + q*4 + rg;
      b2v[mt][rg] = b2[h]; wav[mt][rg] = Wa[h];
    }
  __syncthreads();   // B0

  {
    const size_t fr = (size_t)(b*NT + t0 + w);
    if (l < NJ*NC) xs[w][l] = x[fr*(NJ*NC) + l];
    if (l < NJ*NC) {
      const int ji = l / 3, c = l - ji*3;
      float s = 0.f;
#pragma unroll
      for (int j = 0; j < NJ; ++j) s += afs[ji*NJ + j] * xs[w][j*3 + c];
      ags[w][l] = s;
    }
#pragma unroll
    for (int j = 0; j < NJ; ++j) {
      float v = b1h + w1r0*ags[w][j*3+0] + w1r1*ags[w][j*3+1] + w1r2*ags[w][j*3+2];
      v = fmaxf(v, 0.f);
      h1s[(w*32 + j)*72 + l] = f2bf(v);
    }
  }
  __syncthreads();   // B1

  bf16x8 bw[2][4];
#pragma unroll
  for (int ks = 0; ks < 2; ++ks)
#pragma unroll
    for (int nt = 0; nt < 4; ++nt)
      bw[ks][nt] = *(const bf16x8*)(&w2s[(nt*16 + r)*72 + (ks*4 + q)*8]);
  f32x4 acc1[2][4];
#pragma unroll
  for (int i = 0; i < 2; ++i)
#pragma unroll
    for (int j2 = 0; j2 < 4; ++j2) acc1[i][j2] = (f32x4)0.f;
#pragma unroll
  for (int mti = 0; mti < 2; ++mti) {
    const int row = (w*2 + mti)*16 + r;
#pragma unroll
    for (int ks = 0; ks < 2; ++ks) {
      const bf16x8 af = *(const bf16x8*)(&h1s[row*72 + (ks*4 + q)*8]);
#pragma unroll
      for (int nt = 0; nt < 4; ++nt)
        acc1[mti][nt] = __builtin_amdgcn_mfma_f32_16x16x32_bf16(af, bw[ks][nt], acc1[mti][nt], 0,0,0);
    }
  }
#pragma unroll
  for (int mti = 0; mti < 2; ++mti)
#pragma unroll
    for (int nt = 0; nt < 4; ++nt) {
      const int h = nt*16 + r;
#pragma unroll
      for (int rp = 0; rp < 2; ++rp) {
        const int jp = mti*16 + q*4 + rp*2;
        ((unsigned int*)us)[(w*64 + h)*20 + (jp >> 1)] =
            pk_bf16(acc1[mti][nt][rp*2], acc1[mti][nt][rp*2+1]);
      }
    }
  __syncthreads();   // B2

  bf16x8 badj[2];
#pragma unroll
  for (int nt = 0; nt < 2; ++nt)
    badj[nt] = *(const bf16x8*)(&adjs[(nt*16 + r)*40 + q*8]);
  f32x4 acc2[4][2];
#pragma unroll
  for (int i = 0; i < 4; ++i) { acc2[i][0] = (f32x4)0.f; acc2[i][1] = (f32x4)0.f; }
#pragma unroll
  for (int mt = 0; mt < 4; ++mt) {
    const int h = mt*16 + r;
    const bf16x8 af = *(const bf16x8*)(&us[(w*64 + h)*40 + q*8]);
#pragma unroll
    for (int nt = 0; nt < 2; ++nt)
      acc2[mt][nt] = __builtin_amdgcn_mfma_f32_16x16x32_bf16(af, badj[nt], acc2[mt][nt], 0,0,0);
  }
  float sp0 = 0.f, sp1 = 0.f;
#pragma unroll
  for (int nt = 0; nt < 2; ++nt) {
    const int i = nt*16 + r;
    if (i < NJ) {
#pragma unroll
      for (int mt = 0; mt < 4; ++mt)
#pragma unroll
        for (int rp = 0; rp < 2; ++rp) {
          const int h0 = mt*16 + q*4 + rp*2;
          const float v0 = fmaxf(acc2[mt][nt][rp*2]   + b2v[mt][rp*2],   0.f);
          const float v1 = fmaxf(acc2[mt][nt][rp*2+1] + b2v[mt][rp*2+1], 0.f);
          if (nt == 0) sp0 += v0*wav[mt][rp*2] + v1*wav[mt][rp*2+1];
          else         sp1 += v0*wav[mt][rp*2] + v1*wav[mt][rp*2+1];
          ((unsigned int*)h2st)[(w*NJ + i)*36 + (h0 >> 1)] = pk_bf16(v0, v1);
        }
    }
  }
  sp0 += __shfl_xor(sp0, 16); sp0 += __shfl_xor(sp0, 32);
  sp1 += __shfl_xor(sp1, 16); sp1 += __shfl_xor(sp1, 32);
  if (l < 16) spred[w][l] = sp0;
  if (l < 5)  spred[w][16 + l] = sp1;
  __syncthreads();   // B3

  if (tid < NJ)
    scorepart[((size_t)b*128 + ch)*NJ + tid] =
      spred[0][tid] + spred[1][tid] + spred[2][tid] + spred[3][tid];

  const size_t gbase = (size_t)(b*NT + t0) * JH;
  for (int cid = tid; cid < FB*NJ*8; cid += 256) {
    const int f = cid / (NJ*8), rem = cid - f*(NJ*8);
    const int i = rem >> 3, p = rem & 7;
    const uint4 v = *(const uint4*)(&h2st[(f*NJ + i)*72 + p*8]);
    *(uint4*)(&h2out[gbase + (size_t)f*JH + i*64 + p*8]) = v;
  }
}

// ---------------- K2: reduce score partials, softmax over joints
__global__ __launch_bounds__(64) void k2_attn(
    const float* __restrict__ scorepart, float* __restrict__ attn,
    float* __restrict__ out_attn) {
  __shared__ float ss[NJ];
  const int b = blockIdx.x, tid = threadIdx.x;
  if (tid < NJ) {
    float s = 0.f;
    for (int ch = 0; ch < 128; ++ch) s += scorepart[(b*128 + ch)*NJ + tid];
    ss[tid] = s * (1.0f/NT);
  }
  __syncthreads();
  float m = -1e30f;
  for (int j = 0; j < NJ; ++j) m = fmaxf(m, ss[j]);
  float sum = 0.f;
  for (int j = 0; j < NJ; ++j) sum += expf(ss[j] - m);
  if (tid < NJ) {
    float a = expf(ss[tid] - m) / sum;
    attn[b*NJ + tid] = a;
    out_attn[b*NJ + tid] = a;
  }
}

// ---------------- K3: xproj^T = (h2 * attn) @ W_ih.T + b_ih  -- MFMA bf16
// Output layout [b][g][t] (t-major) so k4 can prefetch 4 steps as float4.
__global__ __launch_bounds__(256, 2) void k3_xproj_mfma(
    const unsigned short* __restrict__ h2, const unsigned short* __restrict__ Wbf,
    const float* __restrict__ b_ih, const float* __restrict__ attn,
    float* __restrict__ xproj) {
  __shared__ unsigned short Abuf[2][128*32];
  __shared__ unsigned short Bbuf[2][192*32];
  const int tid = threadIdx.x;
  const int w = tid >> 6, l = tid & 63;
  const int lq = l >> 4, lr = l & 15;
  const int blk = blockIdx.x;
  const int b = blk >> 2;
  const int t0 = (blk & 3) << 7;
  const int wm = w >> 1, wn = w & 1;

  const unsigned short* gA[2]; int ldsA[2];
#pragma unroll
  for (int i = 0; i < 2; ++i) {
    const int lc = tid*2 + i, rr = lc >> 2, j = lc & 3;
    gA[i] = h2 + (size_t)(b*NT + t0 + rr)*JH + j*8;
    ldsA[i] = rr*32 + ((j ^ ((rr>>1)&3)) << 3);
  }
  const unsigned short* gB[3]; int ldsB[3];
#pragma unroll
  for (int i = 0; i < 3; ++i) {
    const int lc = tid + 256*i, g = lc >> 2, j = lc & 3;
    gB[i] = Wbf + (size_t)g*JH + j*8;
    ldsB[i] = g*32 + ((j ^ ((g>>1)&3)) << 3);
  }
  int aoff[4], boff[6];
#pragma unroll
  for (int mt = 0; mt < 4; ++mt) {
    const int row = wm*64 + mt*16 + lr;
    aoff[mt] = row*32 + ((lq ^ ((row>>1)&3)) << 3);
  }
#pragma unroll
  for (int nt = 0; nt < 6; ++nt) {
    const int g = wn*96 + nt*16 + lr;
    boff[nt] = g*32 + ((lq ^ ((g>>1)&3)) << 3);
  }

  f32x4 acc[4][6];
#pragma unroll
  for (int mt = 0; mt < 4; ++mt)
#pragma unroll
    for (int nt = 0; nt < 6; ++nt) acc[mt][nt] = (f32x4)0.f;

  {
    const float s = attn[b*NJ + 0];
#pragma unroll
    for (int i = 0; i < 2; ++i)
      *(uint4*)(&Abuf[0][ldsA[i]]) = *(const uint4*)(gA[i]);
#pragma unroll
    for (int i = 0; i < 3; ++i) {
      uint4 v = *(const uint4*)(gB[i]);
      v.x = scale2(v.x, s); v.y = scale2(v.y, s);
      v.z = scale2(v.z, s); v.w = scale2(v.w, s);
      *(uint4*)(&Bbuf[0][ldsB[i]]) = v;
    }
  }
  __syncthreads();

  for (int ks = 0; ks < 42; ++ks) {
    const int cur = ks & 1;
    uint4 av0, av1, bv0, bv1, bv2;
    if (ks < 41) {
      const int kk = (ks+1)*32;
      av0 = *(const uint4*)(gA[0] + kk);
      av1 = *(const uint4*)(gA[1] + kk);
      bv0 = *(const uint4*)(gB[0] + kk);
      bv1 = *(const uint4*)(gB[1] + kk);
      bv2 = *(const uint4*)(gB[2] + kk);
    }
    bf16x8 af[4], bfr[6];
#pragma unroll
    for (int mt = 0; mt < 4; ++mt) af[mt] = *(const bf16x8*)(&Abuf[cur][aoff[mt]]);
#pragma unroll
    for (int nt = 0; nt < 6; ++nt) bfr[nt] = *(const bf16x8*)(&Bbuf[cur][boff[nt]]);
#pragma unroll
    for (int mt = 0; mt < 4; ++mt)
#pragma unroll
      for (int nt = 0; nt < 6; ++nt)
        acc[mt][nt] = __builtin_amdgcn_mfma_f32_16x16x32_bf16(af[mt], bfr[nt], acc[mt][nt], 0, 0, 0);
    if (ks < 41) {
      const float s = attn[b*NJ + ((ks+1) >> 1)];
      *(uint4*)(&Abuf[cur^1][ldsA[0]]) = av0;
      *(uint4*)(&Abuf[cur^1][ldsA[1]]) = av1;
      uint4 v;
      v = bv0; v.x = scale2(v.x, s); v.y = scale2(v.y, s); v.z = scale2(v.z, s); v.w = scale2(v.w, s);
      *(uint4*)(&Bbuf[cur^1][ldsB[0]]) = v;
      v = bv1; v.x = scale2(v.x, s); v.y = scale2(v.y, s); v.z = scale2(v.z, s); v.w = scale2(v.w, s);
      *(uint4*)(&Bbuf[cur^1][ldsB[1]]) = v;
      v = bv2; v.x = scale2(v.x, s); v.y = scale2(v.y, s); v.z = scale2(v.z, s); v.w = scale2(v.w, s);
      *(uint4*)(&Bbuf[cur^1][ldsB[2]]) = v;
    }
    __syncthreads();
  }

  float bias[6];
#pragma unroll
  for (int nt = 0; nt < 6; ++nt) bias[nt] = b_ih[wn*96 + nt*16 + lr];
#pragma unroll
  for (int mt = 0; mt < 4; ++mt)
#pragma unroll
    for (int nt = 0; nt < 6; ++nt) {
      const int g = wn*96 + nt*16 + lr;
      const int trow = t0 + wm*64 + mt*16 + lq*4;
      float4 o;
      o.x = acc[mt][nt][0] + bias[nt];
      o.y = acc[mt][nt][1] + bias[nt];
      o.z = acc[mt][nt][2] + bias[nt];
      o.w = acc[mt][nt][3] + bias[nt];
      *(float4*)(&xproj[(size_t)(b*G3 + g)*NT + trow]) = o;
    }
}

// ---------------- K4: MFMA GRU v4. Same decomposition as v3 (16 batches/block,
// 8 blocks, 8 waves, packed ds_write_b32 h-exchange), but per-step sync is now
// raw s_barrier + lgkmcnt(0)-only drain (T4): __syncthreads' implicit
// s_waitcnt vmcnt(0) was draining the 4-deep xproj prefetch every step,
// exposing full HBM latency in the recurrence loop. Global loads now stay in
// flight across barriers; vmcnt waits land only at next-group consumption.
__global__ __launch_bounds__(512, 1) void k4_gru_mfma(
    const float* __restrict__ xproj, const float* __restrict__ W_hh,
    const float* __restrict__ b_hh, float* __restrict__ hT) {
  __shared__ __align__(16) unsigned short hb[2][16*72];  // [buf][batch*72 + ch]
  const int tid = threadIdx.x;
  const int w = tid >> 6, l = tid & 63, q = l >> 4, r15 = l & 15;
  const int b0 = blockIdx.x * 16;

  for (int i = tid; i < 2*16*36; i += 512) ((unsigned int*)hb)[i] = 0u;

  // A-frags: Wg rows permuted so lane (w,q,r15) owns ADJACENT channels
  // {8w+2q, 8w+2q+1}; h writeback is one packed ds_write_b32 (2 lanes/bank).
  bf16x8 afr[2][2];
  int chv[2]; float br_[2], bz_[2], bn_[2];
#pragma unroll
  for (int i = 0; i < 2; ++i) {
    const int mt = 2*w + i;
    const int gate = r15 & 3;
    const int cha = 8*(mt >> 1) + 2*(r15 >> 2) + (mt & 1);  // A-side channel
#pragma unroll
    for (int ks = 0; ks < 2; ++ks) {
      union { bf16x8 v; unsigned int u[4]; } tu;
      if (gate < 3) {
        const float* src = W_hh + (size_t)(gate*NH + cha)*NH + ks*32 + q*8;
        const float4 a = *(const float4*)(src);
        const float4 b = *(const float4*)(src + 4);
        tu.u[0] = pk_bf16(a.x, a.y); tu.u[1] = pk_bf16(a.z, a.w);
        tu.u[2] = pk_bf16(b.x, b.y); tu.u[3] = pk_bf16(b.z, b.w);
      } else {
        tu.u[0]=0u; tu.u[1]=0u; tu.u[2]=0u; tu.u[3]=0u;
      }
      afr[i][ks] = tu.v;
    }
    chv[i] = 8*w + 2*q + i;   // D-side channel this lane owns
    br_[i] = b_hh[chv[i]]; bz_[i] = b_hh[NH + chv[i]]; bn_[i] = b_hh[2*NH + chv[i]];
  }

  const float* xrow[2][3];
#pragma unroll
  for (int i = 0; i < 2; ++i)
#pragma unroll
    for (int e = 0; e < 3; ++e)
      xrow[i][e] = xproj + (size_t)((b0 + r15)*G3 + e*NH + chv[i]) * NT;

  float hprev[2] = {0.f, 0.f};
  __syncthreads();   // once: hb zero-init visible (full drain OK here)

  f32x4 cur[2][3], nxt[2][3];
#pragma unroll
  for (int i = 0; i < 2; ++i)
#pragma unroll
    for (int e = 0; e < 3; ++e) { cur[i][e] = *(const f32x4*)(xrow[i][e]); nxt[i][e] = cur[i][e]; }

  for (int tg = 0; tg < NT; tg += 4) {
    if (tg + 4 < NT) {
#pragma unroll
      for (int i = 0; i < 2; ++i)
#pragma unroll
        for (int e = 0; e < 3; ++e) nxt[i][e] = *(const f32x4*)(xrow[i][e] + tg + 4);
    }
#pragma unroll
    for (int p = 0; p < 4; ++p) {
      const int rb = p & 1, wb = rb ^ 1;
      const bf16x8 bh0 = *(const bf16x8*)(&hb[rb][r15*72 + q*8]);
      const bf16x8 bh1 = *(const bf16x8*)(&hb[rb][r15*72 + 32 + q*8]);
      f32x4 acc[2];
      acc[0] = (f32x4)0.f; acc[1] = (f32x4)0.f;
      acc[0] = __builtin_amdgcn_mfma_f32_16x16x32_bf16(afr[0][0], bh0, acc[0], 0,0,0);
      acc[1] = __builtin_amdgcn_mfma_f32_16x16x32_bf16(afr[1][0], bh0, acc[1], 0,0,0);
      acc[0] = __builtin_amdgcn_mfma_f32_16x16x32_bf16(afr[0][1], bh1, acc[0], 0,0,0);
      acc[1] = __builtin_amdgcn_mfma_f32_16x16x32_bf16(afr[1][1], bh1, acc[1], 0,0,0);
      float hnew[2];
#pragma unroll
      for (int i = 0; i < 2; ++i) {
        const float xr = cur[i][0][p], xz = cur[i][1][p], xn = cur[i][2][p];
        const float hr = acc[i][0] + br_[i];
        const float hz = acc[i][1] + bz_[i];
        const float hn = acc[i][2] + bn_[i];
        const float rr = __builtin_amdgcn_rcpf(1.f + __expf(-(xr + hr)));
        const float zz = __builtin_amdgcn_rcpf(1.f + __expf(-(xz + hz)));
        const float nx = xn + rr*hn;
        const float nn = 2.f*__builtin_amdgcn_rcpf(1.f + __expf(-2.f*nx)) - 1.f;
        hnew[i] = (1.f - zz)*nn + zz*hprev[i];
        hprev[i] = hnew[i];
      }
      ((unsigned int*)&hb[wb][0])[r15*36 + 4*w + q] = pk_bf16(hnew[0], hnew[1]);
      // T4: LDS-only drain + raw barrier -> global prefetch stays in flight
      asm volatile("s_waitcnt lgkmcnt(0)" ::: "memory");
      __builtin_amdgcn_s_barrier();
    }
#pragma unroll
    for (int i = 0; i < 2; ++i)
#pragma unroll
      for (int e = 0; e < 3; ++e) cur[i][e] = nxt[i][e];
  }

#pragma unroll
  for (int i = 0; i < 2; ++i)
    hT[(size_t)(b0 + r15)*NH + chv[i]] = hprev[i];
}

// ---------------- K5: head
__global__ __launch_bounds__(256) void k5_head(
    const float* __restrict__ hT, const float* __restrict__ W_head,
    const float* __restrict__ b_head, float* __restrict__ out) {
  const int idx = blockIdx.x*256 + threadIdx.x;
  if (idx >= NB*63) return;
  const int b = idx / 63, rr = idx % 63;
  const float* hv = hT + b*NH;
  const float* wr = W_head + rr*NH;
  float acc = b_head[rr];
#pragma unroll
  for (int k = 0; k < NH; ++k) acc += hv[k]*wr[k];
  out[idx] = acc;
}

extern "C" void kernel_launch(void* const* d_in, const int* in_sizes, int n_in,
                              void* d_out, int out_size, void* d_ws, size_t ws_size,
                              hipStream_t stream) {
  const float* x      = (const float*)d_in[0];
  const float* A      = (const float*)d_in[1];
  const float* W1     = (const float*)d_in[2];
  const float* b1     = (const float*)d_in[3];
  const float* W2     = (const float*)d_in[4];
  const float* b2     = (const float*)d_in[5];
  const float* Wa     = (const float*)d_in[6];
  // d_in[7] = ba : softmax-invariant, unused
  const float* W_ih   = (const float*)d_in[8];
  const float* b_ih   = (const float*)d_in[9];
  const float* W_hh   = (const float*)d_in[10];
  const float* b_hh   = (const float*)d_in[11];
  const float* W_head = (const float*)d_in[12];
  const float* b_head = (const float*)d_in[13];
  float* out = (float*)d_out;

  char* ws = (char*)d_ws;
  size_t off = 0;
  unsigned short* h2 = (unsigned short*)(ws + off); off += (size_t)NB*NT*JH*2;   // 176 MB
  float* scorepart   = (float*)(ws + off);          off += (size_t)NB*128*NJ*4;  // 1.38 MB
  float* attn        = (float*)(ws + off);          off += (size_t)NB*NJ*4;
  off = (off + 15) & ~(size_t)15;
  float* xproj       = (float*)(ws + off);          off += (size_t)NB*NT*G3*4;   // 50 MB, [b][g][t]
  float* hT          = (float*)(ws + off);          off += (size_t)NB*NH*4;
  off = (off + 15) & ~(size_t)15;
  unsigned short* Wbf = (unsigned short*)(ws + off); off += (size_t)G3*JH*2;     // 516 KB

  k0_convw<<<dim3(252),       256, 0, stream>>>(W_ih, Wbf);
  k1_fused<<<dim3(NB*128),    256, 0, stream>>>(x, A, W1, b1, W2, b2, Wa, h2, scorepart);
  k2_attn<<<dim3(NB),          64, 0, stream>>>(scorepart, attn, out + OUT0);
  k3_xproj_mfma<<<dim3(512),  256, 0, stream>>>(h2, Wbf, b_ih, attn, xproj);
  k4_gru_mfma<<<dim3(8),      512, 0, stream>>>(xproj, W_hh, b_hh, hT);
  k5_head<<<dim3((NB*63 + 255)/256), 256, 0, stream>>>(hT, W_head, b_head, out);
}

// Round 9
// 500.064 us; speedup vs baseline: 1.2415x; 1.0160x over previous
//
#include <hip/hip_runtime.h>
#include <cstdint>
#include <cstddef>

#define NB 128
#define NT 512
#define NJ 21
#define NC 3
#define NH 64
#define JH 1344   // NJ*NH
#define G3 192    // 3*NH
#define OUT0 (NB*NJ*NC) // 8064
#define FB 4      // frames per k1 block (one per wave)

typedef __attribute__((ext_vector_type(8))) __bf16 bf16x8;
typedef __attribute__((ext_vector_type(4))) float f32x4;

__device__ __forceinline__ float bf2f(unsigned short u) {
  union { unsigned int i; float f; } v; v.i = ((unsigned int)u) << 16; return v.f;
}
__device__ __forceinline__ unsigned short f2bf(float f) {
  union { float f; unsigned int i; } v; v.f = f;
  unsigned int x = v.i;
  unsigned int lsb = (x >> 16) & 1u;
  x += 0x7fffu + lsb;
  return (unsigned short)(x >> 16);
}
__device__ __forceinline__ unsigned int pk_bf16(float lo, float hi) {
  unsigned int r;
  asm("v_cvt_pk_bf16_f32 %0, %1, %2" : "=v"(r) : "v"(lo), "v"(hi));
  return r;
}
__device__ __forceinline__ unsigned int scale2(unsigned int u, float s) {
  float lo = __uint_as_float(u << 16);
  float hi = __uint_as_float(u & 0xffff0000u);
  return pk_bf16(lo * s, hi * s);
}

// ---------------- K0: convert W_ih (192x1344 f32) to bf16
__global__ __launch_bounds__(256) void k0_convw(
    const float* __restrict__ W, unsigned short* __restrict__ Wbf) {
  const int ti = blockIdx.x*256 + threadIdx.x;
  const float4 v = ((const float4*)W)[ti];
  uint2 o;
  o.x = (unsigned int)f2bf(v.x) | ((unsigned int)f2bf(v.y) << 16);
  o.y = (unsigned int)f2bf(v.z) | ((unsigned int)f2bf(v.w) << 16);
  ((uint2*)Wbf)[ti] = o;
}

// ---------------- K1: fused GCN x2 via MFMA, linear padded LDS (unchanged, passing)
__global__ __launch_bounds__(256, 2) void k1_fused(
    const float* __restrict__ x, const float* __restrict__ A,
    const float* __restrict__ W1, const float* __restrict__ b1,
    const float* __restrict__ W2, const float* __restrict__ b2,
    const float* __restrict__ Wa,
    unsigned short* __restrict__ h2out, float* __restrict__ scorepart) {
  __shared__ unsigned short h1s[FB*32*72];   // 18 KB  [row][72]
  __shared__ unsigned short us[FB*64*40];    // 20 KB  us[f][h][40]
  __shared__ unsigned short w2s[64*72];      // 9 KB   [h][72]
  __shared__ unsigned short adjs[32*40];     // 2.5 KB [i][40]
  __shared__ unsigned short h2st[FB*NJ*72];  // 11.8 KB [f*21+i][72]
  __shared__ float afs[NJ*NJ];
  __shared__ float xs[4][64];
  __shared__ float ags[4][64];
  __shared__ float spred[4][NJ];

  const int tid = threadIdx.x;
  const int w = tid >> 6, l = tid & 63;
  const int q = l >> 4, r = l & 15;
  const int b = blockIdx.x >> 7, ch = blockIdx.x & 127;
  const int t0 = ch * FB;

  for (int i = tid; i < NJ*NJ; i += 256) afs[i] = A[i];
  for (int i = tid; i < 1024; i += 256) {
    const int ii = i >> 5, jj = i & 31;
    adjs[ii*40 + jj] = (ii < NJ && jj < NJ) ? f2bf(A[ii*NJ + jj]) : (unsigned short)0;
  }
  {
    const int h = tid & 63, qd = tid >> 6;
    const int g0 = qd * 16;
#pragma unroll
    for (int e = 0; e < 16; e += 2) {
      const float v0 = W2[h*64 + g0 + e], v1 = W2[h*64 + g0 + e + 1];
      ((unsigned int*)w2s)[h*36 + ((g0 + e) >> 1)] = pk_bf16(v0, v1);
    }
  }
#pragma unroll
  for (int j = NJ; j < 32; ++j)
    ((unsigned int*)h1s)[(w*32 + j)*36 + (l & 31)] = 0u;

  const float w1r0 = W1[l*3+0], w1r1 = W1[l*3+1], w1r2 = W1[l*3+2];
  const float b1h = b1[l];
  float b2v[4][4], wav[4][4];
#pragma unroll
  for (int mt = 0; mt < 4; ++mt)
#pragma unroll
    for (int rg = 0; rg < 4; ++rg) {
      const int h = mt*16 + q*4 + rg;
      b2v[mt][rg] = b2[h]; wav[mt][rg] = Wa[h];
    }
  __syncthreads();   // B0

  {
    const size_t fr = (size_t)(b*NT + t0 + w);
    if (l < NJ*NC) xs[w][l] = x[fr*(NJ*NC) + l];
    if (l < NJ*NC) {
      const int ji = l / 3, c = l - ji*3;
      float s = 0.f;
#pragma unroll
      for (int j = 0; j < NJ; ++j) s += afs[ji*NJ + j] * xs[w][j*3 + c];
      ags[w][l] = s;
    }
#pragma unroll
    for (int j = 0; j < NJ; ++j) {
      float v = b1h + w1r0*ags[w][j*3+0] + w1r1*ags[w][j*3+1] + w1r2*ags[w][j*3+2];
      v = fmaxf(v, 0.f);
      h1s[(w*32 + j)*72 + l] = f2bf(v);
    }
  }
  __syncthreads();   // B1

  bf16x8 bw[2][4];
#pragma unroll
  for (int ks = 0; ks < 2; ++ks)
#pragma unroll
    for (int nt = 0; nt < 4; ++nt)
      bw[ks][nt] = *(const bf16x8*)(&w2s[(nt*16 + r)*72 + (ks*4 + q)*8]);
  f32x4 acc1[2][4];
#pragma unroll
  for (int i = 0; i < 2; ++i)
#pragma unroll
    for (int j2 = 0; j2 < 4; ++j2) acc1[i][j2] = (f32x4)0.f;
#pragma unroll
  for (int mti = 0; mti < 2; ++mti) {
    const int row = (w*2 + mti)*16 + r;
#pragma unroll
    for (int ks = 0; ks < 2; ++ks) {
      const bf16x8 af = *(const bf16x8*)(&h1s[row*72 + (ks*4 + q)*8]);
#pragma unroll
      for (int nt = 0; nt < 4; ++nt)
        acc1[mti][nt] = __builtin_amdgcn_mfma_f32_16x16x32_bf16(af, bw[ks][nt], acc1[mti][nt], 0,0,0);
    }
  }
#pragma unroll
  for (int mti = 0; mti < 2; ++mti)
#pragma unroll
    for (int nt = 0; nt < 4; ++nt) {
      const int h = nt*16 + r;
#pragma unroll
      for (int rp = 0; rp < 2; ++rp) {
        const int jp = mti*16 + q*4 + rp*2;
        ((unsigned int*)us)[(w*64 + h)*20 + (jp >> 1)] =
            pk_bf16(acc1[mti][nt][rp*2], acc1[mti][nt][rp*2+1]);
      }
    }
  __syncthreads();   // B2

  bf16x8 badj[2];
#pragma unroll
  for (int nt = 0; nt < 2; ++nt)
    badj[nt] = *(const bf16x8*)(&adjs[(nt*16 + r)*40 + q*8]);
  f32x4 acc2[4][2];
#pragma unroll
  for (int i = 0; i < 4; ++i) { acc2[i][0] = (f32x4)0.f; acc2[i][1] = (f32x4)0.f; }
#pragma unroll
  for (int mt = 0; mt < 4; ++mt) {
    const int h = mt*16 + r;
    const bf16x8 af = *(const bf16x8*)(&us[(w*64 + h)*40 + q*8]);
#pragma unroll
    for (int nt = 0; nt < 2; ++nt)
      acc2[mt][nt] = __builtin_amdgcn_mfma_f32_16x16x32_bf16(af, badj[nt], acc2[mt][nt], 0,0,0);
  }
  float sp0 = 0.f, sp1 = 0.f;
#pragma unroll
  for (int nt = 0; nt < 2; ++nt) {
    const int i = nt*16 + r;
    if (i < NJ) {
#pragma unroll
      for (int mt = 0; mt < 4; ++mt)
#pragma unroll
        for (int rp = 0; rp < 2; ++rp) {
          const int h0 = mt*16 + q*4 + rp*2;
          const float v0 = fmaxf(acc2[mt][nt][rp*2]   + b2v[mt][rp*2],   0.f);
          const float v1 = fmaxf(acc2[mt][nt][rp*2+1] + b2v[mt][rp*2+1], 0.f);
          if (nt == 0) sp0 += v0*wav[mt][rp*2] + v1*wav[mt][rp*2+1];
          else         sp1 += v0*wav[mt][rp*2] + v1*wav[mt][rp*2+1];
          ((unsigned int*)h2st)[(w*NJ + i)*36 + (h0 >> 1)] = pk_bf16(v0, v1);
        }
    }
  }
  sp0 += __shfl_xor(sp0, 16); sp0 += __shfl_xor(sp0, 32);
  sp1 += __shfl_xor(sp1, 16); sp1 += __shfl_xor(sp1, 32);
  if (l < 16) spred[w][l] = sp0;
  if (l < 5)  spred[w][16 + l] = sp1;
  __syncthreads();   // B3

  if (tid < NJ)
    scorepart[((size_t)b*128 + ch)*NJ + tid] =
      spred[0][tid] + spred[1][tid] + spred[2][tid] + spred[3][tid];

  const size_t gbase = (size_t)(b*NT + t0) * JH;
  for (int cid = tid; cid < FB*NJ*8; cid += 256) {
    const int f = cid / (NJ*8), rem = cid - f*(NJ*8);
    const int i = rem >> 3, p = rem & 7;
    const uint4 v = *(const uint4*)(&h2st[(f*NJ + i)*72 + p*8]);
    *(uint4*)(&h2out[gbase + (size_t)f*JH + i*64 + p*8]) = v;
  }
}

// ---------------- K2: reduce score partials, softmax over joints
__global__ __launch_bounds__(64) void k2_attn(
    const float* __restrict__ scorepart, float* __restrict__ attn,
    float* __restrict__ out_attn) {
  __shared__ float ss[NJ];
  const int b = blockIdx.x, tid = threadIdx.x;
  if (tid < NJ) {
    float s = 0.f;
    for (int ch = 0; ch < 128; ++ch) s += scorepart[(b*128 + ch)*NJ + tid];
    ss[tid] = s * (1.0f/NT);
  }
  __syncthreads();
  float m = -1e30f;
  for (int j = 0; j < NJ; ++j) m = fmaxf(m, ss[j]);
  float sum = 0.f;
  for (int j = 0; j < NJ; ++j) sum += expf(ss[j] - m);
  if (tid < NJ) {
    float a = expf(ss[tid] - m) / sum;
    attn[b*NJ + tid] = a;
    out_attn[b*NJ + tid] = a;
  }
}

// ---------------- K3: xproj^T = (h2 * attn) @ W_ih.T + bias  -- MFMA bf16
// Output layout [b][g][t]. Bias now folds b_hh for the r/z gates (g < 128):
// k4's hr/hz then come straight off the MFMA accumulator (b_hn stays in k4:
// it sits inside the r-gate product and cannot be folded).
__global__ __launch_bounds__(256, 2) void k3_xproj_mfma(
    const unsigned short* __restrict__ h2, const unsigned short* __restrict__ Wbf,
    const float* __restrict__ b_ih, const float* __restrict__ b_hh,
    const float* __restrict__ attn, float* __restrict__ xproj) {
  __shared__ unsigned short Abuf[2][128*32];
  __shared__ unsigned short Bbuf[2][192*32];
  const int tid = threadIdx.x;
  const int w = tid >> 6, l = tid & 63;
  const int lq = l >> 4, lr = l & 15;
  const int blk = blockIdx.x;
  const int b = blk >> 2;
  const int t0 = (blk & 3) << 7;
  const int wm = w >> 1, wn = w & 1;

  const unsigned short* gA[2]; int ldsA[2];
#pragma unroll
  for (int i = 0; i < 2; ++i) {
    const int lc = tid*2 + i, rr = lc >> 2, j = lc & 3;
    gA[i] = h2 + (size_t)(b*NT + t0 + rr)*JH + j*8;
    ldsA[i] = rr*32 + ((j ^ ((rr>>1)&3)) << 3);
  }
  const unsigned short* gB[3]; int ldsB[3];
#pragma unroll
  for (int i = 0; i < 3; ++i) {
    const int lc = tid + 256*i, g = lc >> 2, j = lc & 3;
    gB[i] = Wbf + (size_t)g*JH + j*8;
    ldsB[i] = g*32 + ((j ^ ((g>>1)&3)) << 3);
  }
  int aoff[4], boff[6];
#pragma unroll
  for (int mt = 0; mt < 4; ++mt) {
    const int row = wm*64 + mt*16 + lr;
    aoff[mt] = row*32 + ((lq ^ ((row>>1)&3)) << 3);
  }
#pragma unroll
  for (int nt = 0; nt < 6; ++nt) {
    const int g = wn*96 + nt*16 + lr;
    boff[nt] = g*32 + ((lq ^ ((g>>1)&3)) << 3);
  }

  f32x4 acc[4][6];
#pragma unroll
  for (int mt = 0; mt < 4; ++mt)
#pragma unroll
    for (int nt = 0; nt < 6; ++nt) acc[mt][nt] = (f32x4)0.f;

  {
    const float s = attn[b*NJ + 0];
#pragma unroll
    for (int i = 0; i < 2; ++i)
      *(uint4*)(&Abuf[0][ldsA[i]]) = *(const uint4*)(gA[i]);
#pragma unroll
    for (int i = 0; i < 3; ++i) {
      uint4 v = *(const uint4*)(gB[i]);
      v.x = scale2(v.x, s); v.y = scale2(v.y, s);
      v.z = scale2(v.z, s); v.w = scale2(v.w, s);
      *(uint4*)(&Bbuf[0][ldsB[i]]) = v;
    }
  }
  __syncthreads();

  for (int ks = 0; ks < 42; ++ks) {
    const int cur = ks & 1;
    uint4 av0, av1, bv0, bv1, bv2;
    if (ks < 41) {
      const int kk = (ks+1)*32;
      av0 = *(const uint4*)(gA[0] + kk);
      av1 = *(const uint4*)(gA[1] + kk);
      bv0 = *(const uint4*)(gB[0] + kk);
      bv1 = *(const uint4*)(gB[1] + kk);
      bv2 = *(const uint4*)(gB[2] + kk);
    }
    bf16x8 af[4], bfr[6];
#pragma unroll
    for (int mt = 0; mt < 4; ++mt) af[mt] = *(const bf16x8*)(&Abuf[cur][aoff[mt]]);
#pragma unroll
    for (int nt = 0; nt < 6; ++nt) bfr[nt] = *(const bf16x8*)(&Bbuf[cur][boff[nt]]);
#pragma unroll
    for (int mt = 0; mt < 4; ++mt)
#pragma unroll
      for (int nt = 0; nt < 6; ++nt)
        acc[mt][nt] = __builtin_amdgcn_mfma_f32_16x16x32_bf16(af[mt], bfr[nt], acc[mt][nt], 0, 0, 0);
    if (ks < 41) {
      const float s = attn[b*NJ + ((ks+1) >> 1)];
      *(uint4*)(&Abuf[cur^1][ldsA[0]]) = av0;
      *(uint4*)(&Abuf[cur^1][ldsA[1]]) = av1;
      uint4 v;
      v = bv0; v.x = scale2(v.x, s); v.y = scale2(v.y, s); v.z = scale2(v.z, s); v.w = scale2(v.w, s);
      *(uint4*)(&Bbuf[cur^1][ldsB[0]]) = v;
      v = bv1; v.x = scale2(v.x, s); v.y = scale2(v.y, s); v.z = scale2(v.z, s); v.w = scale2(v.w, s);
      *(uint4*)(&Bbuf[cur^1][ldsB[1]]) = v;
      v = bv2; v.x = scale2(v.x, s); v.y = scale2(v.y, s); v.z = scale2(v.z, s); v.w = scale2(v.w, s);
      *(uint4*)(&Bbuf[cur^1][ldsB[2]]) = v;
    }
    __syncthreads();
  }

  float bias[6];
#pragma unroll
  for (int nt = 0; nt < 6; ++nt) {
    const int g = wn*96 + nt*16 + lr;
    bias[nt] = b_ih[g] + (g < 2*NH ? b_hh[g] : 0.f);
  }
#pragma unroll
  for (int mt = 0; mt < 4; ++mt)
#pragma unroll
    for (int nt = 0; nt < 6; ++nt) {
      const int g = wn*96 + nt*16 + lr;
      const int trow = t0 + wm*64 + mt*16 + lq*4;
      float4 o;
      o.x = acc[mt][nt][0] + bias[nt];
      o.y = acc[mt][nt][1] + bias[nt];
      o.z = acc[mt][nt][2] + bias[nt];
      o.w = acc[mt][nt][3] + bias[nt];
      *(float4*)(&xproj[(size_t)(b*G3 + g)*NT + trow]) = o;
    }
}

// ---------------- K4: MFMA GRU v5. Same decomposition as v4, but the h
// exchange buffer is stored in LANE-LINEAR consumption order:
// hb4[buf][half][qblk][batch] (uint4 = ch 8*(half*4+qblk)+0..7, batch col).
// Read addr = base + 16*lane -> conflict-free ds_read_b128 (was 8-way:
// 640 conflict-cycles/step serialized on the one LDS pipe right after the
// barrier = the dominant per-step cost). Write: wave w -> dword
// w*64 + 4*r15 + q, 2 lanes/bank = free. r/z biases pre-folded in k3.
__global__ __launch_bounds__(512, 1) void k4_gru_mfma(
    const float* __restrict__ xproj, const float* __restrict__ W_hh,
    const float* __restrict__ b_hh, float* __restrict__ hT) {
  __shared__ __align__(16) uint4 hb4[2][2][4][16];  // 4 KB
  const int tid = threadIdx.x;
  const int w = tid >> 6, l = tid & 63, q = l >> 4, r15 = l & 15;
  const int b0 = blockIdx.x * 16;

  for (int i = tid; i < 256; i += 512) ((uint4*)hb4)[i] = uint4{0u,0u,0u,0u};

  // A-frags: Wg rows permuted so lane (w,q,r15) owns ADJACENT channels
  // {8w+2q, 8w+2q+1}; h writeback is one packed ds_write_b32.
  bf16x8 afr[2][2];
  int chv[2]; float bn_[2];
#pragma unroll
  for (int i = 0; i < 2; ++i) {
    const int mt = 2*w + i;
    const int gate = r15 & 3;
    const int cha = 8*(mt >> 1) + 2*(r15 >> 2) + (mt & 1);  // A-side channel
#pragma unroll
    for (int ks = 0; ks < 2; ++ks) {
      union { bf16x8 v; unsigned int u[4]; } tu;
      if (gate < 3) {
        const float* src = W_hh + (size_t)(gate*NH + cha)*NH + ks*32 + q*8;
        const float4 a = *(const float4*)(src);
        const float4 b = *(const float4*)(src + 4);
        tu.u[0] = pk_bf16(a.x, a.y); tu.u[1] = pk_bf16(a.z, a.w);
        tu.u[2] = pk_bf16(b.x, b.y); tu.u[3] = pk_bf16(b.z, b.w);
      } else {
        tu.u[0]=0u; tu.u[1]=0u; tu.u[2]=0u; tu.u[3]=0u;
      }
      afr[i][ks] = tu.v;
    }
    chv[i] = 8*w + 2*q + i;   // D-side channel this lane owns
    bn_[i] = b_hh[2*NH + chv[i]];
  }
  const int half = w >> 2, qblk = w & 3;

  const float* xrow[2][3];
#pragma unroll
  for (int i = 0; i < 2; ++i)
#pragma unroll
    for (int e = 0; e < 3; ++e)
      xrow[i][e] = xproj + (size_t)((b0 + r15)*G3 + e*NH + chv[i]) * NT;

  float hprev[2] = {0.f, 0.f};
  __syncthreads();   // once: hb4 zero-init visible (full drain OK here)

  f32x4 cur[2][3], nxt[2][3];
#pragma unroll
  for (int i = 0; i < 2; ++i)
#pragma unroll
    for (int e = 0; e < 3; ++e) { cur[i][e] = *(const f32x4*)(xrow[i][e]); nxt[i][e] = cur[i][e]; }

  for (int tg = 0; tg < NT; tg += 4) {
    if (tg + 4 < NT) {
#pragma unroll
      for (int i = 0; i < 2; ++i)
#pragma unroll
        for (int e = 0; e < 3; ++e) nxt[i][e] = *(const f32x4*)(xrow[i][e] + tg + 4);
    }
#pragma unroll
    for (int p = 0; p < 4; ++p) {
      const int rb = p & 1, wb = rb ^ 1;
      const bf16x8 bh0 = *(const bf16x8*)(&hb4[rb][0][q][r15]);
      const bf16x8 bh1 = *(const bf16x8*)(&hb4[rb][1][q][r15]);
      f32x4 acc[2];
      acc[0] = (f32x4)0.f; acc[1] = (f32x4)0.f;
      acc[0] = __builtin_amdgcn_mfma_f32_16x16x32_bf16(afr[0][0], bh0, acc[0], 0,0,0);
      acc[1] = __builtin_amdgcn_mfma_f32_16x16x32_bf16(afr[1][0], bh0, acc[1], 0,0,0);
      acc[0] = __builtin_amdgcn_mfma_f32_16x16x32_bf16(afr[0][1], bh1, acc[0], 0,0,0);
      acc[1] = __builtin_amdgcn_mfma_f32_16x16x32_bf16(afr[1][1], bh1, acc[1], 0,0,0);
      float hnew[2];
#pragma unroll
      for (int i = 0; i < 2; ++i) {
        const float xr = cur[i][0][p], xz = cur[i][1][p], xn = cur[i][2][p];
        const float hn = acc[i][2] + bn_[i];
        const float rr = __builtin_amdgcn_rcpf(1.f + __expf(-(xr + acc[i][0])));
        const float zz = __builtin_amdgcn_rcpf(1.f + __expf(-(xz + acc[i][1])));
        const float nx = xn + rr*hn;
        const float nn = 2.f*__builtin_amdgcn_rcpf(1.f + __expf(-2.f*nx)) - 1.f;
        hnew[i] = nn + zz*(hprev[i] - nn);
        hprev[i] = hnew[i];
      }
      ((unsigned int*)&hb4[wb][half][qblk][r15])[q] = pk_bf16(hnew[0], hnew[1]);
      // T4: LDS-only drain + raw barrier -> global prefetch stays in flight
      asm volatile("s_waitcnt lgkmcnt(0)" ::: "memory");
      __builtin_amdgcn_s_barrier();
    }
#pragma unroll
    for (int i = 0; i < 2; ++i)
#pragma unroll
      for (int e = 0; e < 3; ++e) cur[i][e] = nxt[i][e];
  }

#pragma unroll
  for (int i = 0; i < 2; ++i)
    hT[(size_t)(b0 + r15)*NH + chv[i]] = hprev[i];
}

// ---------------- K5: head
__global__ __launch_bounds__(256) void k5_head(
    const float* __restrict__ hT, const float* __restrict__ W_head,
    const float* __restrict__ b_head, float* __restrict__ out) {
  const int idx = blockIdx.x*256 + threadIdx.x;
  if (idx >= NB*63) return;
  const int b = idx / 63, rr = idx % 63;
  const float* hv = hT + b*NH;
  const float* wr = W_head + rr*NH;
  float acc = b_head[rr];
#pragma unroll
  for (int k = 0; k < NH; ++k) acc += hv[k]*wr[k];
  out[idx] = acc;
}

extern "C" void kernel_launch(void* const* d_in, const int* in_sizes, int n_in,
                              void* d_out, int out_size, void* d_ws, size_t ws_size,
                              hipStream_t stream) {
  const float* x      = (const float*)d_in[0];
  const float* A      = (const float*)d_in[1];
  const float* W1     = (const float*)d_in[2];
  const float* b1     = (const float*)d_in[3];
  const float* W2     = (const float*)d_in[4];
  const float* b2     = (const float*)d_in[5];
  const float* Wa     = (const float*)d_in[6];
  // d_in[7] = ba : softmax-invariant, unused
  const float* W_ih   = (const float*)d_in[8];
  const float* b_ih   = (const float*)d_in[9];
  const float* W_hh   = (const float*)d_in[10];
  const float* b_hh   = (const float*)d_in[11];
  const float* W_head = (const float*)d_in[12];
  const float* b_head = (const float*)d_in[13];
  float* out = (float*)d_out;

  char* ws = (char*)d_ws;
  size_t off = 0;
  unsigned short* h2 = (unsigned short*)(ws + off); off += (size_t)NB*NT*JH*2;   // 176 MB
  float* scorepart   = (float*)(ws + off);          off += (size_t)NB*128*NJ*4;  // 1.38 MB
  float* attn        = (float*)(ws + off);          off += (size_t)NB*NJ*4;
  off = (off + 15) & ~(size_t)15;
  float* xproj       = (float*)(ws + off);          off += (size_t)NB*NT*G3*4;   // 50 MB, [b][g][t]
  float* hT          = (float*)(ws + off);          off += (size_t)NB*NH*4;
  off = (off + 15) & ~(size_t)15;
  unsigned short* Wbf = (unsigned short*)(ws + off); off += (size_t)G3*JH*2;     // 516 KB

  k0_convw<<<dim3(252),       256, 0, stream>>>(W_ih, Wbf);
  k1_fused<<<dim3(NB*128),    256, 0, stream>>>(x, A, W1, b1, W2, b2, Wa, h2, scorepart);
  k2_attn<<<dim3(NB),          64, 0, stream>>>(scorepart, attn, out + OUT0);
  k3_xproj_mfma<<<dim3(512),  256, 0, stream>>>(h2, Wbf, b_ih, b_hh, attn, xproj);
  k4_gru_mfma<<<dim3(8),      512, 0, stream>>>(xproj, W_hh, b_hh, hT);
  k5_head<<<dim3((NB*63 + 255)/256), 256, 0, stream>>>(hT, W_head, b_head, out);
}